// Round 1
// baseline (3353.538 us; speedup 1.0000x reference)
//
#include <hip/hip_runtime.h>
#include <cstddef>

#define HWO 16384   // 128*128
#define CTOT 1536

// ---------------------------------------------------------------------------
// Generic projection: out[b,o,p] = sum_c in[b,c,p] * w[c,o] + bias[o]
// block = 256 threads = 16 positions x 16 o-groups, OPT outputs per thread.
// ---------------------------------------------------------------------------
template<int CIN, int COUT, int OPT>
__global__ __launch_bounds__(256) void proj_kernel(
    const float* __restrict__ in, const float* __restrict__ w,
    const float* __restrict__ bias, float* __restrict__ out,
    int HW, int in_bstride, int out_bstride) {
  static_assert(COUT == 16 * OPT, "COUT must be 16*OPT");
  __shared__ float xt[CIN * 16];
  const int b  = blockIdx.y;
  const int p0 = blockIdx.x * 16;
  const float* inb = in + (size_t)b * in_bstride;
  for (int idx = threadIdx.x; idx < CIN * 16; idx += 256) {
    int c = idx >> 4, p = idx & 15;
    xt[idx] = inb[(size_t)c * HW + (p0 + p)];
  }
  __syncthreads();
  const int pos = threadIdx.x & 15;
  const int og  = (threadIdx.x >> 4) * OPT;
  float acc[OPT];
#pragma unroll
  for (int j = 0; j < OPT; j++) acc[j] = bias[og + j];
  for (int c = 0; c < CIN; c++) {
    float xv = xt[c * 16 + pos];
    const float* wr = w + (size_t)c * COUT + og;
#pragma unroll
    for (int j = 0; j < OPT; j++) acc[j] = fmaf(xv, wr[j], acc[j]);
  }
  float* ob = out + (size_t)b * out_bstride;
  const int gp = p0 + pos;
#pragma unroll
  for (int j = 0; j < OPT; j++) ob[(size_t)(og + j) * HW + gp] = acc[j];
}

// ---------------------------------------------------------------------------
// DySample bilinear upsample for one level.
// grid = (HWO/256, 4 groups, B); out already offset to this level's channels.
// offs layout: (B, 2*4*s*s, H, W); dir0 = x, dir1 = y.
// ---------------------------------------------------------------------------
__global__ __launch_bounds__(256) void upsample_kernel(
    const float* __restrict__ p, const float* __restrict__ offs,
    float* __restrict__ out, int ls, int H, int W) {
  const int b   = blockIdx.z;
  const int grp = blockIdx.y;
  const int op  = blockIdx.x * 256 + threadIdx.x;  // output pixel 0..16383
  const int s   = 1 << ls;
  const int yo = op >> 7, xo = op & 127;
  const int h = yo >> ls, i = yo & (s - 1);
  const int w = xo >> ls, j = xo & (s - 1);
  const int HWs = H * W;
  const int ss  = s * s;
  const float* offb = offs + (size_t)b * 8 * ss * HWs;
  const int sp = h * W + w;
  const float cx = offb[(size_t)(grp * ss + i * s + j) * HWs + sp];
  const float cy = offb[(size_t)((4 + grp) * ss + i * s + j) * HWs + sp];
  const float inv_s = 1.0f / (float)s;
  const float offx = cx * 0.25f + ((float)j - (s - 1) * 0.5f) * inv_s;
  const float offy = cy * 0.25f + ((float)i - (s - 1) * 0.5f) * inv_s;
  float xf = fminf(fmaxf((float)w + offx, 0.0f), (float)(W - 1));
  float yf = fminf(fmaxf((float)h + offy, 0.0f), (float)(H - 1));
  float x0f = floorf(xf), y0f = floorf(yf);
  int x0 = (int)x0f, y0 = (int)y0f;
  int x1 = min(x0 + 1, W - 1), y1 = min(y0 + 1, H - 1);
  float wx = xf - x0f, wy = yf - y0f;
  float w00 = (1.f - wx) * (1.f - wy), w01 = wx * (1.f - wy);
  float w10 = (1.f - wx) * wy,         w11 = wx * wy;
  const int i00 = y0 * W + x0, i01 = y0 * W + x1;
  const int i10 = y1 * W + x0, i11 = y1 * W + x1;
  const float* pb = p + ((size_t)b * 384 + grp * 96) * HWs;
  float* ob = out + (size_t)b * CTOT * HWO + (size_t)grp * 96 * HWO + op;
  for (int cg = 0; cg < 96; cg++) {
    const float* pc = pb + (size_t)cg * HWs;
    float v = w00 * pc[i00] + w01 * pc[i01] + w10 * pc[i10] + w11 * pc[i11];
    ob[(size_t)cg * HWO] = v;
  }
}

// ---------------------------------------------------------------------------
// Per-(b,c) spatial mean of cc. grid = 3072, block = 256.
// ---------------------------------------------------------------------------
__global__ __launch_bounds__(256) void colmean_kernel(
    const float* __restrict__ cc, float* __restrict__ sout) {
  const int bc = blockIdx.x;
  const float* p = cc + (size_t)bc * HWO;
  float a = 0.f;
  for (int i = threadIdx.x; i < HWO; i += 256) a += p[i];
  for (int o = 32; o > 0; o >>= 1) a += __shfl_down(a, o, 64);
  __shared__ float red[4];
  if ((threadIdx.x & 63) == 0) red[threadIdx.x >> 6] = a;
  __syncthreads();
  if (threadIdx.x == 0)
    sout[bc] = (red[0] + red[1] + red[2] + red[3]) * (1.0f / HWO);
}

// ---------------------------------------------------------------------------
// SSM prep: per (b,c) compute u(64), proj(33), dt(64); emit u, Cs, dA, dBu.
// grid = 3072, block = 64 (one wave).
// ---------------------------------------------------------------------------
__global__ __launch_bounds__(64) void ssm_prep(
    const float* __restrict__ s, const float* __restrict__ in_w,
    const float* __restrict__ in_b, const float* __restrict__ xproj_w,
    const float* __restrict__ dt_w, const float* __restrict__ dt_b,
    const float* __restrict__ A_log,
    float* __restrict__ u_out, float* __restrict__ Cs_out,
    float* __restrict__ dA_out, float* __restrict__ dBu_out) {
  const int bc = blockIdx.x;
  const int d  = threadIdx.x;
  const float sv = s[bc];
  const float u = sv * in_w[d] + in_b[d];
  __shared__ float ush[64];
  __shared__ float proj[33];
  ush[d] = u;
  __syncthreads();
  if (d < 33) {
    float a = 0.f;
    for (int k = 0; k < 64; k++) a = fmaf(ush[k], xproj_w[k * 33 + d], a);
    proj[d] = a;
  }
  __syncthreads();
  float dtv = proj[0] * dt_w[d] + dt_b[d];
  dtv = (dtv > 20.0f) ? dtv : log1pf(__expf(dtv));   // softplus
  u_out[(size_t)bc * 64 + d] = u;
  if (d < 16) Cs_out[(size_t)bc * 16 + d] = proj[17 + d];
  const float du = dtv * u;
  const size_t base = (size_t)bc * 1024 + (size_t)d * 16;
#pragma unroll
  for (int n = 0; n < 16; n++) {
    float A = -__expf(A_log[d * 16 + n]);
    dA_out[base + n]  = __expf(dtv * A);
    dBu_out[base + n] = du * proj[1 + n];
  }
}

// ---------------------------------------------------------------------------
// Sequential scan over the 1536 channels. grid = 4 (b x dir), block = 256:
// thread t -> d = t>>2 (0..63), q = t&3 (4 states n = 4q..4q+3 each).
// ---------------------------------------------------------------------------
__global__ __launch_bounds__(256) void ssm_scan(
    const float4* __restrict__ dA4, const float4* __restrict__ dBu4,
    const float4* __restrict__ Cs4, float* __restrict__ y) {
  const int b = blockIdx.x >> 1, dir = blockIdx.x & 1;
  const int t = threadIdx.x, d = t >> 2, q = t & 3;
  float h0 = 0.f, h1 = 0.f, h2 = 0.f, h3 = 0.f;
  float* yb = y + (size_t)(b * 2 + dir) * 1536 * 64;
  int c = dir ? 1535 : 0;
  const int step = dir ? -1 : 1;
  for (int st = 0; st < 1536; st++, c += step) {
    const size_t bc = (size_t)b * 1536 + c;
    const float4 a  = dA4[bc * 256 + d * 4 + q];
    const float4 db = dBu4[bc * 256 + d * 4 + q];
    const float4 cn = Cs4[bc * 4 + q];
    h0 = fmaf(a.x, h0, db.x);
    h1 = fmaf(a.y, h1, db.y);
    h2 = fmaf(a.z, h2, db.z);
    h3 = fmaf(a.w, h3, db.w);
    float ctr = h0 * cn.x + h1 * cn.y + h2 * cn.z + h3 * cn.w;
    ctr += __shfl_xor(ctr, 1, 64);
    ctr += __shfl_xor(ctr, 2, 64);
    if (q == 0) yb[(size_t)c * 64 + d] = ctr;
  }
}

// ---------------------------------------------------------------------------
// Gate: yt = y_fwd + y_bwd + D*u; gate = sigmoid(yt . out_w + out_b).
// grid = (1536, B), block = 64.
// ---------------------------------------------------------------------------
__global__ __launch_bounds__(64) void gate_kernel(
    const float* __restrict__ y, const float* __restrict__ u,
    const float* __restrict__ Dp, const float* __restrict__ out_w,
    const float* __restrict__ out_b, float* __restrict__ gate) {
  const int c = blockIdx.x, b = blockIdx.y, d = threadIdx.x;
  const size_t i = ((size_t)b * 1536 + c) * 64 + d;
  float yt = y[((size_t)(b * 2) * 1536 + c) * 64 + d]
           + y[((size_t)(b * 2 + 1) * 1536 + c) * 64 + d]
           + Dp[d] * u[i];
  float v = yt * out_w[d];
  for (int o = 32; o > 0; o >>= 1) v += __shfl_down(v, o, 64);
  if (d == 0) gate[b * 1536 + c] = 1.0f / (1.0f + __expf(-(v + out_b[0])));
}

// ---------------------------------------------------------------------------
// Fused: h = (cc*gate) @ fuse_w  -> BN -> ReLU -> pred/bird heads.
// grid = (1024, B), block = 256 (16 pos x 16 o-groups x 24 outputs).
// ---------------------------------------------------------------------------
__global__ __launch_bounds__(256) void fuse_kernel(
    const float* __restrict__ cc, const float* __restrict__ gate,
    const float* __restrict__ fuse_w,
    const float* __restrict__ bn_g, const float* __restrict__ bn_b,
    const float* __restrict__ bn_m, const float* __restrict__ bn_v,
    const float* __restrict__ pred_w, const float* __restrict__ pred_b,
    const float* __restrict__ bird_w, const float* __restrict__ bird_b,
    float* __restrict__ out) {
  __shared__ float xt[128 * 16];
  __shared__ float hl[384 * 16];
  const int b  = blockIdx.y;
  const int p0 = blockIdx.x * 16;
  const float* ccb = cc + (size_t)b * CTOT * HWO;
  const float* gb  = gate + b * 1536;
  const int pos = threadIdx.x & 15;
  const int og  = (threadIdx.x >> 4) * 24;
  float acc[24];
#pragma unroll
  for (int j = 0; j < 24; j++) acc[j] = 0.f;
  for (int kc = 0; kc < 1536; kc += 128) {
    __syncthreads();
    for (int idx = threadIdx.x; idx < 128 * 16; idx += 256) {
      int c = idx >> 4, p = idx & 15;
      xt[idx] = ccb[(size_t)(kc + c) * HWO + (p0 + p)] * gb[kc + c];
    }
    __syncthreads();
    for (int c = 0; c < 128; c++) {
      float xv = xt[c * 16 + pos];
      const float* wr = fuse_w + (size_t)(kc + c) * 384 + og;
#pragma unroll
      for (int j = 0; j < 24; j++) acc[j] = fmaf(xv, wr[j], acc[j]);
    }
  }
  __syncthreads();
#pragma unroll
  for (int j = 0; j < 24; j++) {
    const int o = og + j;
    float sc = bn_g[o] * rsqrtf(bn_v[o] + 1e-5f);
    float hv = (acc[j] - bn_m[o]) * sc + bn_b[o];
    hl[o * 16 + pos] = fmaxf(hv, 0.f);
  }
  __syncthreads();
  if (threadIdx.x < 128) {
    const int och = threadIdx.x >> 4;
    const int p   = threadIdx.x & 15;
    const float* w; float bias; int stride, col; float* optr;
    if (och < 6) {
      w = pred_w; col = och; stride = 6; bias = pred_b[och];
      optr = out + ((size_t)b * 6 + och) * HWO;
    } else {
      w = bird_w; col = och - 6; stride = 2; bias = bird_b[och - 6];
      optr = out + (size_t)2 * 6 * HWO + ((size_t)b * 2 + (och - 6)) * HWO;
    }
    float a2 = bias;
    for (int o = 0; o < 384; o++) a2 = fmaf(hl[o * 16 + p], w[o * stride + col], a2);
    optr[p0 + p] = a2;
  }
}

// ---------------------------------------------------------------------------
extern "C" void kernel_launch(void* const* d_in, const int* in_sizes, int n_in,
                              void* d_out, int out_size, void* d_ws, size_t ws_size,
                              hipStream_t stream) {
  const float* c1      = (const float*)d_in[0];
  const float* c2      = (const float*)d_in[1];
  const float* c3      = (const float*)d_in[2];
  const float* c4      = (const float*)d_in[3];
  const float* mlp1_w  = (const float*)d_in[4];
  const float* mlp1_b  = (const float*)d_in[5];
  const float* mlp2_w  = (const float*)d_in[6];
  const float* mlp2_b  = (const float*)d_in[7];
  const float* mlp3_w  = (const float*)d_in[8];
  const float* mlp3_b  = (const float*)d_in[9];
  const float* mlp4_w  = (const float*)d_in[10];
  const float* mlp4_b  = (const float*)d_in[11];
  const float* up2_w   = (const float*)d_in[12];
  const float* up2_b   = (const float*)d_in[13];
  const float* up4_w   = (const float*)d_in[14];
  const float* up4_b   = (const float*)d_in[15];
  const float* up8_w   = (const float*)d_in[16];
  const float* up8_b   = (const float*)d_in[17];
  const float* ssm_in_w   = (const float*)d_in[18];
  const float* ssm_in_b   = (const float*)d_in[19];
  const float* ssm_xproj_w= (const float*)d_in[20];
  const float* ssm_dt_w   = (const float*)d_in[21];
  const float* ssm_dt_b   = (const float*)d_in[22];
  const float* ssm_A_log  = (const float*)d_in[23];
  const float* ssm_D      = (const float*)d_in[24];
  const float* ssm_out_w  = (const float*)d_in[25];
  const float* ssm_out_b  = (const float*)d_in[26];
  const float* fuse_w  = (const float*)d_in[27];
  const float* bn_g    = (const float*)d_in[28];
  const float* bn_b    = (const float*)d_in[29];
  const float* bn_m    = (const float*)d_in[30];
  const float* bn_v    = (const float*)d_in[31];
  const float* pred_w  = (const float*)d_in[32];
  const float* pred_b  = (const float*)d_in[33];
  const float* bird_w  = (const float*)d_in[34];
  const float* bird_b  = (const float*)d_in[35];
  float* outp = (float*)d_out;

  float* ws = (float*)d_ws;
  size_t off = 0;
  auto alloc = [&](size_t n) { float* p = ws + off; off += n; return p; };
  float* cc   = alloc((size_t)2 * CTOT * HWO);   // (B,1536,128,128)
  float* p4   = alloc((size_t)2 * 384 * 256);
  float* p3   = alloc((size_t)2 * 384 * 1024);
  float* p2   = alloc((size_t)2 * 384 * 4096);
  float* o4   = alloc((size_t)2 * 512 * 256);
  float* o3   = alloc((size_t)2 * 128 * 1024);
  float* o2   = alloc((size_t)2 * 32 * 4096);
  float* sbuf = alloc(3072);
  float* ubuf = alloc((size_t)2 * 1536 * 64);
  float* Csb  = alloc((size_t)2 * 1536 * 16);
  float* dAb  = alloc((size_t)2 * 1536 * 1024);
  float* dBub = alloc((size_t)2 * 1536 * 1024);
  float* yb   = alloc((size_t)2 * 2 * 1536 * 64);
  float* gteb = alloc(3072);
  (void)ws_size; (void)in_sizes; (void)n_in; (void)out_size;

  // 1) feature projections
  hipLaunchKernelGGL((proj_kernel<96, 384, 24>), dim3(HWO / 16, 2), dim3(256), 0, stream,
                     c1, mlp1_w, mlp1_b, cc + (size_t)1152 * HWO, HWO, 96 * HWO, CTOT * HWO);
  hipLaunchKernelGGL((proj_kernel<384, 384, 24>), dim3(256 / 16, 2), dim3(256), 0, stream,
                     c4, mlp4_w, mlp4_b, p4, 256, 384 * 256, 384 * 256);
  hipLaunchKernelGGL((proj_kernel<192, 384, 24>), dim3(1024 / 16, 2), dim3(256), 0, stream,
                     c3, mlp3_w, mlp3_b, p3, 1024, 192 * 1024, 384 * 1024);
  hipLaunchKernelGGL((proj_kernel<96, 384, 24>), dim3(4096 / 16, 2), dim3(256), 0, stream,
                     c2, mlp2_w, mlp2_b, p2, 4096, 96 * 4096, 384 * 4096);
  // 2) offset convs
  hipLaunchKernelGGL((proj_kernel<384, 512, 32>), dim3(256 / 16, 2), dim3(256), 0, stream,
                     p4, up8_w, up8_b, o4, 256, 384 * 256, 512 * 256);
  hipLaunchKernelGGL((proj_kernel<384, 128, 8>), dim3(1024 / 16, 2), dim3(256), 0, stream,
                     p3, up4_w, up4_b, o3, 1024, 384 * 1024, 128 * 1024);
  hipLaunchKernelGGL((proj_kernel<384, 32, 2>), dim3(4096 / 16, 2), dim3(256), 0, stream,
                     p2, up2_w, up2_b, o2, 4096, 384 * 4096, 32 * 4096);
  // 3) dysample upsampling into cc
  hipLaunchKernelGGL(upsample_kernel, dim3(HWO / 256, 4, 2), dim3(256), 0, stream,
                     p4, o4, cc, 3, 16, 16);
  hipLaunchKernelGGL(upsample_kernel, dim3(HWO / 256, 4, 2), dim3(256), 0, stream,
                     p3, o3, cc + (size_t)384 * HWO, 2, 32, 32);
  hipLaunchKernelGGL(upsample_kernel, dim3(HWO / 256, 4, 2), dim3(256), 0, stream,
                     p2, o2, cc + (size_t)768 * HWO, 1, 64, 64);
  // 4) spatial means
  hipLaunchKernelGGL(colmean_kernel, dim3(3072), dim3(256), 0, stream, cc, sbuf);
  // 5) ssm prep + scan + gate
  hipLaunchKernelGGL(ssm_prep, dim3(3072), dim3(64), 0, stream,
                     sbuf, ssm_in_w, ssm_in_b, ssm_xproj_w, ssm_dt_w, ssm_dt_b,
                     ssm_A_log, ubuf, Csb, dAb, dBub);
  hipLaunchKernelGGL(ssm_scan, dim3(4), dim3(256), 0, stream,
                     (const float4*)dAb, (const float4*)dBub, (const float4*)Csb, yb);
  hipLaunchKernelGGL(gate_kernel, dim3(1536, 2), dim3(64), 0, stream,
                     yb, ubuf, ssm_D, ssm_out_w, ssm_out_b, gteb);
  // 6) fused gate*cc @ fuse_w -> BN -> ReLU -> heads
  hipLaunchKernelGGL(fuse_kernel, dim3(HWO / 16, 2), dim3(256), 0, stream,
                     cc, gteb, fuse_w, bn_g, bn_b, bn_m, bn_v,
                     pred_w, pred_b, bird_w, bird_b, outp);
}

// Round 2
// 955.271 us; speedup vs baseline: 3.5106x; 3.5106x over previous
//
#include <hip/hip_runtime.h>
#include <cstddef>

#define HWO 16384   // 128*128
#define CTOT 1536

typedef __attribute__((ext_vector_type(8))) short bf16x8;
typedef __attribute__((ext_vector_type(4))) float f32x4;

__device__ inline unsigned short f2bf(float x) {
  union { float f; unsigned u; } v; v.f = x;
  unsigned r = v.u + 0x7FFFu + ((v.u >> 16) & 1u);
  return (unsigned short)(r >> 16);
}
__device__ inline float bf2f(unsigned short h) {
  union { unsigned u; float f; } v; v.u = ((unsigned)h) << 16; return v.f;
}

// ---------------------------------------------------------------------------
// Weight transpose + bf16 convert: W[K][N] f32 -> Wt[N][K] bf16.
// Optional per-k gate fold (for the fuse GEMM).
// ---------------------------------------------------------------------------
__global__ __launch_bounds__(256) void transpose_w_bf16(
    const float* __restrict__ W, unsigned short* __restrict__ Wt,
    int K, int N, const float* __restrict__ gate) {
  const int idx = blockIdx.x * 256 + threadIdx.x;
  if (idx >= K * N) return;
  const int k = idx / N, o = idx - k * N;
  float v = W[idx];
  if (gate) v *= gate[k];
  Wt[(size_t)o * K + k] = f2bf(v);
}

__global__ __launch_bounds__(256) void bnfold_kernel(
    const float* __restrict__ g, const float* __restrict__ var,
    const float* __restrict__ m, const float* __restrict__ bb,
    float* __restrict__ sc, float* __restrict__ sh) {
  const int o = blockIdx.x * 256 + threadIdx.x;
  if (o < 384) {
    const float s = g[o] * rsqrtf(var[o] + 1e-5f);
    sc[o] = s;
    sh[o] = bb[o] - m[o] * s;
  }
}

// ---------------------------------------------------------------------------
// Generic MFMA GEMM: Y[b,o,p] = sum_k X[b,k,p] * W[k,o] (+bias / +BN-relu-bf16)
// X: f32 [B][K][P]; Wt: bf16 [ (B) ][N][K] pre-transposed.
// Block: 256 threads (4 waves), tile 64 positions x N outputs.
// SPLITN: waves split otiles (OT each, share 4 ptiles); else waves split ptiles.
// ---------------------------------------------------------------------------
template<int K, int NT, int OT, bool SPLITN, bool OUT_BF16>
__global__ __launch_bounds__(256) void mfma_gemm(
    const float* __restrict__ X, const unsigned short* __restrict__ Wt,
    const float* __restrict__ bias, const float* __restrict__ ep_a,
    const float* __restrict__ ep_b, void* __restrict__ Yv,
    int P, long x_bs, long wt_bs, long y_bs) {
  constexpr int N = NT * 16;
  static_assert(!SPLITN || NT == OT * 4, "NT must equal OT*4 in SPLITN mode");
  __shared__ unsigned short Alds[64 * 40];   // [pos][k(32)+pad8]
  __shared__ unsigned short Blds[N * 40];    // [o][k(32)+pad8]
  const int tid = threadIdx.x;
  const int w = tid >> 6, lane = tid & 63;
  const int b = blockIdx.y;
  const int p0 = blockIdx.x * 64;
  const float* Xb = X + (long)b * x_bs;
  const unsigned short* Wb = Wt + (long)b * wt_bs;
  constexpr int NACC = SPLITN ? OT * 4 : NT;
  f32x4 acc[NACC];
#pragma unroll
  for (int i = 0; i < NACC; i++) acc[i] = (f32x4){0.f, 0.f, 0.f, 0.f};
  const int ch = tid >> 3, ps = (tid & 7) * 8;
  const int lr = lane & 15, lk = (lane >> 4) * 8;

  for (int kc = 0; kc < K; kc += 32) {
    // stage A: 32 ch x 64 pos f32 -> bf16 LDS [pos][ch]
    const float* xp = Xb + (long)(kc + ch) * P + (p0 + ps);
    const float4 v0 = *(const float4*)xp;
    const float4 v1 = *(const float4*)(xp + 4);
    Alds[(ps + 0) * 40 + ch] = f2bf(v0.x);
    Alds[(ps + 1) * 40 + ch] = f2bf(v0.y);
    Alds[(ps + 2) * 40 + ch] = f2bf(v0.z);
    Alds[(ps + 3) * 40 + ch] = f2bf(v0.w);
    Alds[(ps + 4) * 40 + ch] = f2bf(v1.x);
    Alds[(ps + 5) * 40 + ch] = f2bf(v1.y);
    Alds[(ps + 6) * 40 + ch] = f2bf(v1.z);
    Alds[(ps + 7) * 40 + ch] = f2bf(v1.w);
    // stage B: N rows x 32 k, 16B chunks
    for (int idx = tid; idx < N * 4; idx += 256) {
      const int o = idx >> 2, ck = (idx & 3) * 8;
      *(uint4*)(&Blds[o * 40 + ck]) =
          *(const uint4*)(Wb + (long)o * K + kc + ck);
    }
    __syncthreads();
    if constexpr (SPLITN) {
      bf16x8 af[4];
#pragma unroll
      for (int pt = 0; pt < 4; pt++)
        af[pt] = *(const bf16x8*)(&Alds[(pt * 16 + lr) * 40 + lk]);
#pragma unroll
      for (int ot = 0; ot < OT; ot++) {
        const bf16x8 bf_ =
            *(const bf16x8*)(&Blds[((w * OT + ot) * 16 + lr) * 40 + lk]);
#pragma unroll
        for (int pt = 0; pt < 4; pt++)
          acc[ot * 4 + pt] = __builtin_amdgcn_mfma_f32_16x16x32_bf16(
              af[pt], bf_, acc[ot * 4 + pt], 0, 0, 0);
      }
    } else {
      const bf16x8 af = *(const bf16x8*)(&Alds[(w * 16 + lr) * 40 + lk]);
#pragma unroll
      for (int ot = 0; ot < NT; ot++) {
        const bf16x8 bf_ = *(const bf16x8*)(&Blds[(ot * 16 + lr) * 40 + lk]);
        acc[ot] =
            __builtin_amdgcn_mfma_f32_16x16x32_bf16(af, bf_, acc[ot], 0, 0, 0);
      }
    }
    __syncthreads();
  }
  // store: C/D layout col=lane&15 (output), row=(lane>>4)*4+reg (position)
  const int r0 = (lane >> 4) * 4;
#pragma unroll
  for (int i = 0; i < NACC; i++) {
    int o, prow;
    if constexpr (SPLITN) {
      o = (w * OT + (i >> 2)) * 16 + lr;
      prow = p0 + (i & 3) * 16 + r0;
    } else {
      o = i * 16 + lr;
      prow = p0 + w * 16 + r0;
    }
    const f32x4 r = acc[i];
    if constexpr (OUT_BF16) {
      const float sa = ep_a[o], sb = ep_b[o];
      ushort4 hv;
      hv.x = f2bf(fmaxf(fmaf(r[0], sa, sb), 0.f));
      hv.y = f2bf(fmaxf(fmaf(r[1], sa, sb), 0.f));
      hv.z = f2bf(fmaxf(fmaf(r[2], sa, sb), 0.f));
      hv.w = f2bf(fmaxf(fmaf(r[3], sa, sb), 0.f));
      *(ushort4*)((unsigned short*)Yv + (long)b * y_bs + (long)o * P + prow) = hv;
    } else {
      const float bv = bias ? bias[o] : 0.f;
      const float4 rv = make_float4(r[0] + bv, r[1] + bv, r[2] + bv, r[3] + bv);
      *(float4*)((float*)Yv + (long)b * y_bs + (long)o * P + prow) = rv;
    }
  }
}

// ---------------------------------------------------------------------------
// DySample bilinear upsample for one level (unchanged from working version).
// ---------------------------------------------------------------------------
__global__ __launch_bounds__(256) void upsample_kernel(
    const float* __restrict__ p, const float* __restrict__ offs,
    float* __restrict__ out, int ls, int H, int W) {
  const int b   = blockIdx.z;
  const int grp = blockIdx.y;
  const int op  = blockIdx.x * 256 + threadIdx.x;
  const int s   = 1 << ls;
  const int yo = op >> 7, xo = op & 127;
  const int h = yo >> ls, i = yo & (s - 1);
  const int w = xo >> ls, j = xo & (s - 1);
  const int HWs = H * W;
  const int ss  = s * s;
  const float* offb = offs + (size_t)b * 8 * ss * HWs;
  const int sp = h * W + w;
  const float cx = offb[(size_t)(grp * ss + i * s + j) * HWs + sp];
  const float cy = offb[(size_t)((4 + grp) * ss + i * s + j) * HWs + sp];
  const float inv_s = 1.0f / (float)s;
  const float offx = cx * 0.25f + ((float)j - (s - 1) * 0.5f) * inv_s;
  const float offy = cy * 0.25f + ((float)i - (s - 1) * 0.5f) * inv_s;
  float xf = fminf(fmaxf((float)w + offx, 0.0f), (float)(W - 1));
  float yf = fminf(fmaxf((float)h + offy, 0.0f), (float)(H - 1));
  float x0f = floorf(xf), y0f = floorf(yf);
  int x0 = (int)x0f, y0 = (int)y0f;
  int x1 = min(x0 + 1, W - 1), y1 = min(y0 + 1, H - 1);
  float wx = xf - x0f, wy = yf - y0f;
  float w00 = (1.f - wx) * (1.f - wy), w01 = wx * (1.f - wy);
  float w10 = (1.f - wx) * wy,         w11 = wx * wy;
  const int i00 = y0 * W + x0, i01 = y0 * W + x1;
  const int i10 = y1 * W + x0, i11 = y1 * W + x1;
  const float* pb = p + ((size_t)b * 384 + grp * 96) * HWs;
  float* ob = out + (size_t)b * CTOT * HWO + (size_t)grp * 96 * HWO + op;
  for (int cg = 0; cg < 96; cg++) {
    const float* pc = pb + (size_t)cg * HWs;
    float v = w00 * pc[i00] + w01 * pc[i01] + w10 * pc[i10] + w11 * pc[i11];
    ob[(size_t)cg * HWO] = v;
  }
}

// ---------------------------------------------------------------------------
// Per-(b,c) spatial mean of cc (float4 loads). grid = 3072, block = 256.
// ---------------------------------------------------------------------------
__global__ __launch_bounds__(256) void colmean_kernel(
    const float* __restrict__ cc, float* __restrict__ sout) {
  const int bc = blockIdx.x;
  const float4* p = (const float4*)(cc + (size_t)bc * HWO);
  float a = 0.f;
  for (int i = threadIdx.x; i < HWO / 4; i += 256) {
    const float4 v = p[i];
    a += (v.x + v.y) + (v.z + v.w);
  }
  for (int o = 32; o > 0; o >>= 1) a += __shfl_down(a, o, 64);
  __shared__ float red[4];
  if ((threadIdx.x & 63) == 0) red[threadIdx.x >> 6] = a;
  __syncthreads();
  if (threadIdx.x == 0)
    sout[bc] = (red[0] + red[1] + red[2] + red[3]) * (1.0f / HWO);
}

// ---------------------------------------------------------------------------
// SSM prep: per (b,c): u(64), proj(33), dt(64). Emit u, dt, dt*u, Bs, Cs.
// grid = 3072, block = 64.
// ---------------------------------------------------------------------------
__global__ __launch_bounds__(64) void ssm_prep(
    const float* __restrict__ s, const float* __restrict__ in_w,
    const float* __restrict__ in_b, const float* __restrict__ xproj_w,
    const float* __restrict__ dt_w, const float* __restrict__ dt_b,
    float* __restrict__ u_out, float* __restrict__ dt_out,
    float* __restrict__ dtu_out, float* __restrict__ Bs_out,
    float* __restrict__ Cs_out) {
  const int bc = blockIdx.x;
  const int d  = threadIdx.x;
  const float sv = s[bc];
  const float u = sv * in_w[d] + in_b[d];
  __shared__ float ush[64];
  __shared__ float proj[33];
  ush[d] = u;
  __syncthreads();
  if (d < 33) {
    float a = 0.f;
    for (int k = 0; k < 64; k++) a = fmaf(ush[k], xproj_w[k * 33 + d], a);
    proj[d] = a;
  }
  __syncthreads();
  float dtv = proj[0] * dt_w[d] + dt_b[d];
  dtv = (dtv > 20.0f) ? dtv : log1pf(__expf(dtv));   // softplus
  u_out[(size_t)bc * 64 + d] = u;
  dt_out[(size_t)bc * 64 + d] = dtv;
  dtu_out[(size_t)bc * 64 + d] = dtv * u;
  if (d < 16) {
    Bs_out[(size_t)bc * 16 + d] = proj[1 + d];
    Cs_out[(size_t)bc * 16 + d] = proj[17 + d];
  }
}

// ---------------------------------------------------------------------------
// Sequential scan over 1536 channels; dA/dBu computed in-loop from tiny
// per-channel arrays (dt, dt*u, Bs) with explicit next-channel prefetch.
// grid = 4 (b x dir), block = 256 (d = t>>2, q = t&3 -> 4 states each).
// ---------------------------------------------------------------------------
__global__ __launch_bounds__(256) void ssm_scan(
    const float* __restrict__ dt_g, const float* __restrict__ dtu_g,
    const float4* __restrict__ Bs4, const float4* __restrict__ Cs4,
    const float* __restrict__ A_log, float* __restrict__ y) {
  const int b = blockIdx.x >> 1, dir = blockIdx.x & 1;
  const int t = threadIdx.x, d = t >> 2, q = t & 3;
  const float4 Al = ((const float4*)A_log)[d * 4 + q];
  const float A0 = -__expf(Al.x), A1 = -__expf(Al.y);
  const float A2 = -__expf(Al.z), A3 = -__expf(Al.w);
  float h0 = 0.f, h1 = 0.f, h2 = 0.f, h3 = 0.f;
  float* yb = y + (size_t)(b * 2 + dir) * 1536 * 64;
  int c = dir ? 1535 : 0;
  const int step = dir ? -1 : 1;
  size_t bc = (size_t)b * 1536 + c;
  float dtv = dt_g[bc * 64 + d];
  float duv = dtu_g[bc * 64 + d];
  float4 Bv = Bs4[bc * 4 + q];
  float4 Cv = Cs4[bc * 4 + q];
  for (int st = 0; st < 1536; st++) {
    const float dt_c = dtv, du_c = duv;
    const float4 B_c = Bv, C_c = Cv;
    const int cur = c;
    c += step;
    if (st + 1 < 1536) {
      const size_t bcn = (size_t)b * 1536 + c;
      dtv = dt_g[bcn * 64 + d];
      duv = dtu_g[bcn * 64 + d];
      Bv = Bs4[bcn * 4 + q];
      Cv = Cs4[bcn * 4 + q];
    }
    h0 = fmaf(__expf(dt_c * A0), h0, du_c * B_c.x);
    h1 = fmaf(__expf(dt_c * A1), h1, du_c * B_c.y);
    h2 = fmaf(__expf(dt_c * A2), h2, du_c * B_c.z);
    h3 = fmaf(__expf(dt_c * A3), h3, du_c * B_c.w);
    float ctr = h0 * C_c.x + h1 * C_c.y + h2 * C_c.z + h3 * C_c.w;
    ctr += __shfl_xor(ctr, 1, 64);
    ctr += __shfl_xor(ctr, 2, 64);
    if (q == 0) yb[(size_t)cur * 64 + d] = ctr;
  }
}

// ---------------------------------------------------------------------------
// Gate: yt = y_fwd + y_bwd + D*u; gate = sigmoid(yt . out_w + out_b).
// ---------------------------------------------------------------------------
__global__ __launch_bounds__(64) void gate_kernel(
    const float* __restrict__ y, const float* __restrict__ u,
    const float* __restrict__ Dp, const float* __restrict__ out_w,
    const float* __restrict__ out_b, float* __restrict__ gate) {
  const int c = blockIdx.x, b = blockIdx.y, d = threadIdx.x;
  const size_t i = ((size_t)b * 1536 + c) * 64 + d;
  float yt = y[((size_t)(b * 2) * 1536 + c) * 64 + d]
           + y[((size_t)(b * 2 + 1) * 1536 + c) * 64 + d]
           + Dp[d] * u[i];
  float v = yt * out_w[d];
  for (int o = 32; o > 0; o >>= 1) v += __shfl_down(v, o, 64);
  if (d == 0) gate[b * 1536 + c] = 1.0f / (1.0f + __expf(-(v + out_b[0])));
}

// ---------------------------------------------------------------------------
// Heads: out = h_relu @ pred_w + pred_b; aux = h_relu @ bird_w + bird_b.
// h is bf16, already BN'd+ReLU'd. grid = 128, block = 256.
// ---------------------------------------------------------------------------
__global__ __launch_bounds__(256) void head_kernel(
    const unsigned short* __restrict__ h,
    const float* __restrict__ pred_w, const float* __restrict__ pred_b,
    const float* __restrict__ bird_w, const float* __restrict__ bird_b,
    float* __restrict__ out) {
  const int idx = blockIdx.x * 256 + threadIdx.x;
  const int b = idx >> 14, p = idx & 16383;
  const unsigned short* hb = h + (size_t)b * 384 * HWO + p;
  float a0 = pred_b[0], a1 = pred_b[1], a2 = pred_b[2];
  float a3 = pred_b[3], a4 = pred_b[4], a5 = pred_b[5];
  float a6 = bird_b[0], a7 = bird_b[1];
  for (int o = 0; o < 384; o++) {
    const float hv = bf2f(hb[(size_t)o * HWO]);
    const float* pw = pred_w + o * 6;
    a0 = fmaf(hv, pw[0], a0);
    a1 = fmaf(hv, pw[1], a1);
    a2 = fmaf(hv, pw[2], a2);
    a3 = fmaf(hv, pw[3], a3);
    a4 = fmaf(hv, pw[4], a4);
    a5 = fmaf(hv, pw[5], a5);
    a6 = fmaf(hv, bird_w[o * 2 + 0], a6);
    a7 = fmaf(hv, bird_w[o * 2 + 1], a7);
  }
  float* ob = out + (size_t)b * 6 * HWO + p;
  ob[0] = a0; ob[HWO] = a1; ob[2 * HWO] = a2;
  ob[3 * HWO] = a3; ob[4 * HWO] = a4; ob[5 * HWO] = a5;
  float* ab = out + (size_t)12 * HWO + (size_t)b * 2 * HWO + p;
  ab[0] = a6; ab[HWO] = a7;
}

// ---------------------------------------------------------------------------
extern "C" void kernel_launch(void* const* d_in, const int* in_sizes, int n_in,
                              void* d_out, int out_size, void* d_ws, size_t ws_size,
                              hipStream_t stream) {
  const float* c1      = (const float*)d_in[0];
  const float* c2      = (const float*)d_in[1];
  const float* c3      = (const float*)d_in[2];
  const float* c4      = (const float*)d_in[3];
  const float* mlp1_w  = (const float*)d_in[4];
  const float* mlp1_b  = (const float*)d_in[5];
  const float* mlp2_w  = (const float*)d_in[6];
  const float* mlp2_b  = (const float*)d_in[7];
  const float* mlp3_w  = (const float*)d_in[8];
  const float* mlp3_b  = (const float*)d_in[9];
  const float* mlp4_w  = (const float*)d_in[10];
  const float* mlp4_b  = (const float*)d_in[11];
  const float* up2_w   = (const float*)d_in[12];
  const float* up2_b   = (const float*)d_in[13];
  const float* up4_w   = (const float*)d_in[14];
  const float* up4_b   = (const float*)d_in[15];
  const float* up8_w   = (const float*)d_in[16];
  const float* up8_b   = (const float*)d_in[17];
  const float* ssm_in_w    = (const float*)d_in[18];
  const float* ssm_in_b    = (const float*)d_in[19];
  const float* ssm_xproj_w = (const float*)d_in[20];
  const float* ssm_dt_w    = (const float*)d_in[21];
  const float* ssm_dt_b    = (const float*)d_in[22];
  const float* ssm_A_log   = (const float*)d_in[23];
  const float* ssm_D       = (const float*)d_in[24];
  const float* ssm_out_w   = (const float*)d_in[25];
  const float* ssm_out_b   = (const float*)d_in[26];
  const float* fuse_w  = (const float*)d_in[27];
  const float* bn_g    = (const float*)d_in[28];
  const float* bn_b    = (const float*)d_in[29];
  const float* bn_m    = (const float*)d_in[30];
  const float* bn_v    = (const float*)d_in[31];
  const float* pred_w  = (const float*)d_in[32];
  const float* pred_b  = (const float*)d_in[33];
  const float* bird_w  = (const float*)d_in[34];
  const float* bird_b  = (const float*)d_in[35];
  float* outp = (float*)d_out;
  (void)in_sizes; (void)n_in; (void)out_size; (void)ws_size;

  float* ws = (float*)d_ws;
  size_t off = 0;
  auto alloc = [&](size_t n) { float* p = ws + off; off += n; return p; };
  float* cc      = alloc((size_t)2 * CTOT * HWO);     // 50,331,648 fl
  float* scratch = alloc(6291456);                    // p*/o*; later aliased by hbf
  float* bp4 = scratch;                 // 2*384*256   = 196,608
  float* bp3 = scratch + 196608;        // 2*384*1024  = 786,432
  float* bp2 = scratch + 983040;        // 2*384*4096  = 3,145,728
  float* bo4 = scratch + 4128768;       // 2*512*256   = 262,144
  float* bo3 = scratch + 4390912;       // 2*128*1024  = 262,144
  float* bo2 = scratch + 4653056;       // 2*32*4096   = 262,144
  unsigned short* hbf = (unsigned short*)scratch;     // 2*384*16384 bf16 (alias)
  float* sbuf = alloc(3072);
  float* ub   = alloc(196608);
  float* dtb  = alloc(196608);
  float* dtub = alloc(196608);
  float* Bsb  = alloc(49152);
  float* Csb  = alloc(49152);
  float* yb   = alloc(393216);
  float* gteb = alloc(3072);
  float* scb  = alloc(384);
  float* shb  = alloc(384);
  unsigned short* wt0 = (unsigned short*)(ws + off);
  unsigned short* t1  = wt0;             // 96*384
  unsigned short* t2  = t1 + 36864;      // 96*384
  unsigned short* t3  = t2 + 36864;      // 192*384
  unsigned short* t4  = t3 + 73728;      // 384*384
  unsigned short* t8  = t4 + 147456;     // 384*512
  unsigned short* t4u = t8 + 196608;     // 384*128
  unsigned short* t2u = t4u + 49152;     // 384*32
  unsigned short* wg  = t2u + 12288;     // 2*384*1536

  auto TP = [&](const float* W, unsigned short* T, int K_, int N_, const float* g) {
    const int n = K_ * N_;
    hipLaunchKernelGGL(transpose_w_bf16, dim3((n + 255) / 256), dim3(256), 0,
                       stream, W, T, K_, N_, g);
  };
  // 0) weight transposes (bf16) + BN fold
  TP(mlp1_w, t1, 96, 384, nullptr);
  TP(mlp2_w, t2, 96, 384, nullptr);
  TP(mlp3_w, t3, 192, 384, nullptr);
  TP(mlp4_w, t4, 384, 384, nullptr);
  TP(up8_w, t8, 384, 512, nullptr);
  TP(up4_w, t4u, 384, 128, nullptr);
  TP(up2_w, t2u, 384, 32, nullptr);
  hipLaunchKernelGGL(bnfold_kernel, dim3(2), dim3(256), 0, stream,
                     bn_g, bn_v, bn_m, bn_b, scb, shb);

  // 1) feature projections (MFMA)
  hipLaunchKernelGGL((mfma_gemm<96, 24, 6, true, false>), dim3(256, 2), dim3(256), 0, stream,
      c1, t1, mlp1_b, nullptr, nullptr, (void*)(cc + (size_t)1152 * HWO),
      HWO, (long)96 * HWO, 0L, (long)CTOT * HWO);
  hipLaunchKernelGGL((mfma_gemm<384, 24, 6, true, false>), dim3(4, 2), dim3(256), 0, stream,
      c4, t4, mlp4_b, nullptr, nullptr, (void*)bp4, 256, (long)384 * 256, 0L, (long)384 * 256);
  hipLaunchKernelGGL((mfma_gemm<192, 24, 6, true, false>), dim3(16, 2), dim3(256), 0, stream,
      c3, t3, mlp3_b, nullptr, nullptr, (void*)bp3, 1024, (long)192 * 1024, 0L, (long)384 * 1024);
  hipLaunchKernelGGL((mfma_gemm<96, 24, 6, true, false>), dim3(64, 2), dim3(256), 0, stream,
      c2, t2, mlp2_b, nullptr, nullptr, (void*)bp2, 4096, (long)96 * 4096, 0L, (long)384 * 4096);
  // 2) offset convs (MFMA)
  hipLaunchKernelGGL((mfma_gemm<384, 32, 8, true, false>), dim3(4, 2), dim3(256), 0, stream,
      bp4, t8, up8_b, nullptr, nullptr, (void*)bo4, 256, (long)384 * 256, 0L, (long)512 * 256);
  hipLaunchKernelGGL((mfma_gemm<384, 8, 2, true, false>), dim3(16, 2), dim3(256), 0, stream,
      bp3, t4u, up4_b, nullptr, nullptr, (void*)bo3, 1024, (long)384 * 1024, 0L, (long)128 * 1024);
  hipLaunchKernelGGL((mfma_gemm<384, 2, 1, false, false>), dim3(64, 2), dim3(256), 0, stream,
      bp2, t2u, up2_b, nullptr, nullptr, (void*)bo2, 4096, (long)384 * 4096, 0L, (long)32 * 4096);
  // 3) dysample upsampling into cc
  hipLaunchKernelGGL(upsample_kernel, dim3(HWO / 256, 4, 2), dim3(256), 0, stream,
                     bp4, bo4, cc, 3, 16, 16);
  hipLaunchKernelGGL(upsample_kernel, dim3(HWO / 256, 4, 2), dim3(256), 0, stream,
                     bp3, bo3, cc + (size_t)384 * HWO, 2, 32, 32);
  hipLaunchKernelGGL(upsample_kernel, dim3(HWO / 256, 4, 2), dim3(256), 0, stream,
                     bp2, bo2, cc + (size_t)768 * HWO, 1, 64, 64);
  // 4) spatial means
  hipLaunchKernelGGL(colmean_kernel, dim3(3072), dim3(256), 0, stream, cc, sbuf);
  // 5) ssm prep + scan + gate
  hipLaunchKernelGGL(ssm_prep, dim3(3072), dim3(64), 0, stream,
                     sbuf, ssm_in_w, ssm_in_b, ssm_xproj_w, ssm_dt_w, ssm_dt_b,
                     ub, dtb, dtub, Bsb, Csb);
  hipLaunchKernelGGL(ssm_scan, dim3(4), dim3(256), 0, stream,
                     dtb, dtub, (const float4*)Bsb, (const float4*)Csb,
                     ssm_A_log, yb);
  hipLaunchKernelGGL(gate_kernel, dim3(1536, 2), dim3(64), 0, stream,
                     yb, ub, ssm_D, ssm_out_w, ssm_out_b, gteb);
  // 6) gate-folded fuse weights (per batch), then fused GEMM + BN + ReLU
  TP(fuse_w, wg, 1536, 384, gteb);
  TP(fuse_w, wg + 589824, 1536, 384, gteb + 1536);
  hipLaunchKernelGGL((mfma_gemm<1536, 24, 6, true, true>), dim3(256, 2), dim3(256), 0, stream,
      cc, wg, nullptr, scb, shb, (void*)hbf,
      HWO, (long)CTOT * HWO, (long)384 * 1536, (long)384 * HWO);
  // 7) heads
  hipLaunchKernelGGL(head_kernel, dim3(128), dim3(256), 0, stream,
                     hbf, pred_w, pred_b, bird_w, bird_b, outp);
}

// Round 3
// 501.063 us; speedup vs baseline: 6.6929x; 1.9065x over previous
//
#include <hip/hip_runtime.h>
#include <cstddef>

#define HWO 16384   // 128*128
#define CTOT 1536

typedef __attribute__((ext_vector_type(8))) short bf16x8;
typedef __attribute__((ext_vector_type(4))) float f32x4;

__device__ inline unsigned short f2bf(float x) {
  union { float f; unsigned u; } v; v.f = x;
  unsigned r = v.u + 0x7FFFu + ((v.u >> 16) & 1u);
  return (unsigned short)(r >> 16);
}
__device__ inline float bf2f(unsigned short h) {
  union { unsigned u; float f; } v; v.u = ((unsigned)h) << 16; return v.f;
}

// ---------------------------------------------------------------------------
// Batched static weight transposes: W[K][N] f32 -> Wt[N][K] bf16 (7 specs).
// ---------------------------------------------------------------------------
struct TP7 {
  const float* W[7];
  unsigned short* T[7];
  int K[7], N[7], bstart[8];
};
__global__ __launch_bounds__(256) void transpose7_kernel(TP7 sp) {
  int s = 0;
#pragma unroll
  for (int i = 1; i < 7; i++) if ((int)blockIdx.x >= sp.bstart[i]) s = i;
  const int K = sp.K[s], N = sp.N[s];
  const int idx = (blockIdx.x - sp.bstart[s]) * 256 + threadIdx.x;
  if (idx >= K * N) return;
  const int k = idx / N, o = idx - k * N;
  sp.T[s][(size_t)o * K + k] = f2bf(sp.W[s][idx]);
}

// fuse_w transpose with per-batch gate fold: grid (blocks, 2)
__global__ __launch_bounds__(256) void transpose_fuse(
    const float* __restrict__ W, const float* __restrict__ gate,
    unsigned short* __restrict__ Wt) {
  const int b = blockIdx.y;
  const int idx = blockIdx.x * 256 + threadIdx.x;
  if (idx >= 1536 * 384) return;
  const int k = idx / 384, o = idx - k * 384;
  Wt[(size_t)b * 589824 + (size_t)o * 1536 + k] =
      f2bf(W[idx] * gate[b * 1536 + k]);
}

__global__ __launch_bounds__(256) void bnfold_kernel(
    const float* __restrict__ g, const float* __restrict__ var,
    const float* __restrict__ m, const float* __restrict__ bb,
    float* __restrict__ sc, float* __restrict__ sh) {
  const int o = blockIdx.x * 256 + threadIdx.x;
  if (o < 384) {
    const float s = g[o] * rsqrtf(var[o] + 1e-5f);
    sc[o] = s;
    sh[o] = bb[o] - m[o] * s;
  }
}

// ---------------------------------------------------------------------------
// Generic MFMA GEMM: Y[b,o,p] = sum_k X[b,k,p] * W[k,o] (+bias / +BN-relu)
// X: f32 or bf16 [B][K][P]; Wt: bf16 [(B)][N][K] pre-transposed.
// Block: 256 threads (4 waves), tile 64 positions x N outputs.
// ---------------------------------------------------------------------------
template<int K, int NT, int OT, bool SPLITN, bool OUT_BF16, bool XBF16>
__global__ __launch_bounds__(256) void mfma_gemm(
    const void* __restrict__ Xv, const unsigned short* __restrict__ Wt,
    const float* __restrict__ bias, const float* __restrict__ ep_a,
    const float* __restrict__ ep_b, void* __restrict__ Yv,
    int P, long x_bs, long wt_bs, long y_bs) {
  constexpr int N = NT * 16;
  static_assert(!SPLITN || NT == OT * 4, "NT must equal OT*4 in SPLITN mode");
  __shared__ unsigned short Alds[64 * 40];   // [pos][k(32)+pad8]
  __shared__ unsigned short Blds[N * 40];    // [o][k(32)+pad8]
  const int tid = threadIdx.x;
  const int w = tid >> 6, lane = tid & 63;
  const int b = blockIdx.y;
  const int p0 = blockIdx.x * 64;
  const unsigned short* Wb = Wt + (long)b * wt_bs;
  constexpr int NACC = SPLITN ? OT * 4 : NT;
  f32x4 acc[NACC];
#pragma unroll
  for (int i = 0; i < NACC; i++) acc[i] = (f32x4){0.f, 0.f, 0.f, 0.f};
  const int ch = tid >> 3, ps = (tid & 7) * 8;
  const int lr = lane & 15, lk = (lane >> 4) * 8;

  for (int kc = 0; kc < K; kc += 32) {
    // stage A: 32 ch x 64 pos -> bf16 LDS [pos][ch]
    if constexpr (XBF16) {
      const unsigned short* xp =
          (const unsigned short*)Xv + (long)b * x_bs + (long)(kc + ch) * P + (p0 + ps);
      uint4 v = *(const uint4*)xp;
      const unsigned short* s8 = (const unsigned short*)&v;
#pragma unroll
      for (int j = 0; j < 8; j++) Alds[(ps + j) * 40 + ch] = s8[j];
    } else {
      const float* xp = (const float*)Xv + (long)b * x_bs + (long)(kc + ch) * P + (p0 + ps);
      const float4 v0 = *(const float4*)xp;
      const float4 v1 = *(const float4*)(xp + 4);
      Alds[(ps + 0) * 40 + ch] = f2bf(v0.x);
      Alds[(ps + 1) * 40 + ch] = f2bf(v0.y);
      Alds[(ps + 2) * 40 + ch] = f2bf(v0.z);
      Alds[(ps + 3) * 40 + ch] = f2bf(v0.w);
      Alds[(ps + 4) * 40 + ch] = f2bf(v1.x);
      Alds[(ps + 5) * 40 + ch] = f2bf(v1.y);
      Alds[(ps + 6) * 40 + ch] = f2bf(v1.z);
      Alds[(ps + 7) * 40 + ch] = f2bf(v1.w);
    }
    // stage B: N rows x 32 k, 16B chunks
    for (int idx = tid; idx < N * 4; idx += 256) {
      const int o = idx >> 2, ck = (idx & 3) * 8;
      *(uint4*)(&Blds[o * 40 + ck]) = *(const uint4*)(Wb + (long)o * K + kc + ck);
    }
    __syncthreads();
    if constexpr (SPLITN) {
      bf16x8 af[4];
#pragma unroll
      for (int pt = 0; pt < 4; pt++)
        af[pt] = *(const bf16x8*)(&Alds[(pt * 16 + lr) * 40 + lk]);
#pragma unroll
      for (int ot = 0; ot < OT; ot++) {
        const bf16x8 bf_ = *(const bf16x8*)(&Blds[((w * OT + ot) * 16 + lr) * 40 + lk]);
#pragma unroll
        for (int pt = 0; pt < 4; pt++)
          acc[ot * 4 + pt] = __builtin_amdgcn_mfma_f32_16x16x32_bf16(
              af[pt], bf_, acc[ot * 4 + pt], 0, 0, 0);
      }
    } else {
      const bf16x8 af = *(const bf16x8*)(&Alds[(w * 16 + lr) * 40 + lk]);
#pragma unroll
      for (int ot = 0; ot < NT; ot++) {
        const bf16x8 bf_ = *(const bf16x8*)(&Blds[(ot * 16 + lr) * 40 + lk]);
        acc[ot] = __builtin_amdgcn_mfma_f32_16x16x32_bf16(af, bf_, acc[ot], 0, 0, 0);
      }
    }
    __syncthreads();
  }
  // store: C/D layout col=lane&15 (output o), row=(lane>>4)*4+reg (position)
  const int r0 = (lane >> 4) * 4;
#pragma unroll
  for (int i = 0; i < NACC; i++) {
    int o, prow;
    if constexpr (SPLITN) {
      o = (w * OT + (i >> 2)) * 16 + lr;
      prow = p0 + (i & 3) * 16 + r0;
    } else {
      o = i * 16 + lr;
      prow = p0 + w * 16 + r0;
    }
    const f32x4 r = acc[i];
    const float bv = bias ? bias[o] : 0.f;
    if constexpr (OUT_BF16) {
      ushort4 hv;
      if (ep_a) {
        const float sa = ep_a[o], sb = ep_b[o];
        hv.x = f2bf(fmaxf(fmaf(r[0] + bv, sa, sb), 0.f));
        hv.y = f2bf(fmaxf(fmaf(r[1] + bv, sa, sb), 0.f));
        hv.z = f2bf(fmaxf(fmaf(r[2] + bv, sa, sb), 0.f));
        hv.w = f2bf(fmaxf(fmaf(r[3] + bv, sa, sb), 0.f));
      } else {
        hv.x = f2bf(r[0] + bv); hv.y = f2bf(r[1] + bv);
        hv.z = f2bf(r[2] + bv); hv.w = f2bf(r[3] + bv);
      }
      *(ushort4*)((unsigned short*)Yv + (long)b * y_bs + (long)o * P + prow) = hv;
    } else {
      const float4 rv = make_float4(r[0] + bv, r[1] + bv, r[2] + bv, r[3] + bv);
      *(float4*)((float*)Yv + (long)b * y_bs + (long)o * P + prow) = rv;
    }
  }
}

// ---------------------------------------------------------------------------
// DySample bilinear upsample (f32 in, bf16 out into cc).
// ---------------------------------------------------------------------------
__global__ __launch_bounds__(256) void upsample_kernel(
    const float* __restrict__ p, const float* __restrict__ offs,
    unsigned short* __restrict__ out, int ls, int H, int W) {
  const int b   = blockIdx.z;
  const int grp = blockIdx.y;
  const int op  = blockIdx.x * 256 + threadIdx.x;
  const int s   = 1 << ls;
  const int yo = op >> 7, xo = op & 127;
  const int h = yo >> ls, i = yo & (s - 1);
  const int w = xo >> ls, j = xo & (s - 1);
  const int HWs = H * W;
  const int ss  = s * s;
  const float* offb = offs + (size_t)b * 8 * ss * HWs;
  const int sp = h * W + w;
  const float cx = offb[(size_t)(grp * ss + i * s + j) * HWs + sp];
  const float cy = offb[(size_t)((4 + grp) * ss + i * s + j) * HWs + sp];
  const float inv_s = 1.0f / (float)s;
  const float offx = cx * 0.25f + ((float)j - (s - 1) * 0.5f) * inv_s;
  const float offy = cy * 0.25f + ((float)i - (s - 1) * 0.5f) * inv_s;
  float xf = fminf(fmaxf((float)w + offx, 0.0f), (float)(W - 1));
  float yf = fminf(fmaxf((float)h + offy, 0.0f), (float)(H - 1));
  float x0f = floorf(xf), y0f = floorf(yf);
  int x0 = (int)x0f, y0 = (int)y0f;
  int x1 = min(x0 + 1, W - 1), y1 = min(y0 + 1, H - 1);
  float wx = xf - x0f, wy = yf - y0f;
  float w00 = (1.f - wx) * (1.f - wy), w01 = wx * (1.f - wy);
  float w10 = (1.f - wx) * wy,         w11 = wx * wy;
  const int i00 = y0 * W + x0, i01 = y0 * W + x1;
  const int i10 = y1 * W + x0, i11 = y1 * W + x1;
  const float* pb = p + ((size_t)b * 384 + grp * 96) * HWs;
  unsigned short* ob = out + (size_t)b * CTOT * HWO + (size_t)grp * 96 * HWO + op;
  for (int cg = 0; cg < 96; cg++) {
    const float* pc = pb + (size_t)cg * HWs;
    float v = w00 * pc[i00] + w01 * pc[i01] + w10 * pc[i10] + w11 * pc[i11];
    ob[(size_t)cg * HWO] = f2bf(v);
  }
}

// ---------------------------------------------------------------------------
// Per-(b,c) spatial mean of bf16 cc. grid = 3072, block = 256.
// ---------------------------------------------------------------------------
__global__ __launch_bounds__(256) void colmean_kernel(
    const unsigned short* __restrict__ cc, float* __restrict__ sout) {
  const int bc = blockIdx.x;
  const uint4* p = (const uint4*)(cc + (size_t)bc * HWO);
  float a = 0.f;
  for (int i = threadIdx.x; i < HWO / 8; i += 256) {
    const uint4 v = p[i];
    const unsigned short* s = (const unsigned short*)&v;
#pragma unroll
    for (int k = 0; k < 8; k++) a += bf2f(s[k]);
  }
  for (int o = 32; o > 0; o >>= 1) a += __shfl_down(a, o, 64);
  __shared__ float red[4];
  if ((threadIdx.x & 63) == 0) red[threadIdx.x >> 6] = a;
  __syncthreads();
  if (threadIdx.x == 0)
    sout[bc] = (red[0] + red[1] + red[2] + red[3]) * (1.0f / HWO);
}

// ---------------------------------------------------------------------------
// SSM prep: per (b,c): u(64), proj(33), dt. Emit u, packed (dt,dt*u), Bs, Cs.
// grid = 3072, block = 64.
// ---------------------------------------------------------------------------
__global__ __launch_bounds__(64) void ssm_prep(
    const float* __restrict__ s, const float* __restrict__ in_w,
    const float* __restrict__ in_b, const float* __restrict__ xproj_w,
    const float* __restrict__ dt_w, const float* __restrict__ dt_b,
    float* __restrict__ u_out, float2* __restrict__ dtdu_out,
    float* __restrict__ Bs_out, float* __restrict__ Cs_out) {
  const int bc = blockIdx.x;
  const int d  = threadIdx.x;
  const float sv = s[bc];
  const float u = sv * in_w[d] + in_b[d];
  __shared__ float ush[64];
  __shared__ float proj[33];
  ush[d] = u;
  __syncthreads();
  if (d < 33) {
    float a = 0.f;
    for (int k = 0; k < 64; k++) a = fmaf(ush[k], xproj_w[k * 33 + d], a);
    proj[d] = a;
  }
  __syncthreads();
  float dtv = proj[0] * dt_w[d] + dt_b[d];
  dtv = (dtv > 20.0f) ? dtv : log1pf(__expf(dtv));   // softplus
  u_out[(size_t)bc * 64 + d] = u;
  dtdu_out[(size_t)bc * 64 + d] = make_float2(dtv, dtv * u);
  if (d < 16) {
    Bs_out[(size_t)bc * 16 + d] = proj[1 + d];
    Cs_out[(size_t)bc * 16 + d] = proj[17 + d];
  }
}

// ---------------------------------------------------------------------------
// Parallel associative scan. grid = (64 d, 2 dir, 2 b), block = 256.
// thread t: chunk j = t>>4 (16 chunks of 96 channels), state n = t&15.
// Pass1: per-chunk composition (Ap,Bp). LDS scan gives carry-in. Pass2: emit y.
// ---------------------------------------------------------------------------
__global__ __launch_bounds__(256) void ssm_scan_par(
    const float2* __restrict__ dtdu, const float* __restrict__ Bs,
    const float* __restrict__ Cs, const float* __restrict__ A_log,
    float* __restrict__ y) {
  const int d = blockIdx.x, dir = blockIdx.y, b = blockIdx.z;
  const int t = threadIdx.x;
  const int j = t >> 4, n = t & 15;
  const float A = -__expf(A_log[d * 16 + n]);
  const int s0 = j * 96;
  const int c0 = dir ? (1535 - s0) : s0;
  const int step = dir ? -1 : 1;
  const float2* dbase = dtdu + (size_t)b * 1536 * 64 + (size_t)c0 * 64 + d;
  const float* bbase = Bs + (size_t)b * 1536 * 16 + (size_t)c0 * 16 + n;
  const float* cbase = Cs + (size_t)b * 1536 * 16 + (size_t)c0 * 16 + n;
  const long dstep = (long)step * 64;
  const long bstep = (long)step * 16;

  // pass 1: chunk composition
  float Ap = 1.f, Bp = 0.f;
  {
    const float2* dp = dbase;
    const float* bp = bbase;
    float2 td = *dp;
    float Bv = *bp;
    for (int i = 0; i < 96; i++) {
      const float2 tdc = td;
      const float Bc = Bv;
      dp += dstep; bp += bstep;
      if (i + 1 < 96) { td = *dp; Bv = *bp; }
      const float a = __expf(tdc.x * A);
      Bp = fmaf(a, Bp, tdc.y * Bc);
      Ap *= a;
    }
  }
  __shared__ float sA[16][16], sB[16][16];
  sA[j][n] = Ap;
  sB[j][n] = Bp;
  __syncthreads();
  float H = 0.f;
  for (int jj = 0; jj < j; jj++) H = fmaf(sA[jj][n], H, sB[jj][n]);

  // pass 2: replay with carry-in, emit y
  float* yb = y + (size_t)(b * 2 + dir) * 1536 * 64;
  {
    const float2* dp = dbase;
    const float* bp = bbase;
    const float* cp = cbase;
    float2 td = *dp;
    float Bv = *bp;
    float Cv = *cp;
    float h = H;
    int c = c0;
    for (int i = 0; i < 96; i++) {
      const float2 tdc = td;
      const float Bc = Bv, Cc = Cv;
      dp += dstep; bp += bstep; cp += bstep;
      if (i + 1 < 96) { td = *dp; Bv = *bp; Cv = *cp; }
      const float a = __expf(tdc.x * A);
      h = fmaf(a, h, tdc.y * Bc);
      float pr = h * Cc;
      pr += __shfl_xor(pr, 1, 64);
      pr += __shfl_xor(pr, 2, 64);
      pr += __shfl_xor(pr, 4, 64);
      pr += __shfl_xor(pr, 8, 64);
      if (n == 0) yb[(size_t)c * 64 + d] = pr;
      c += step;
    }
  }
}

// ---------------------------------------------------------------------------
// Gate: yt = y_fwd + y_bwd + D*u; gate = sigmoid(yt . out_w + out_b).
// ---------------------------------------------------------------------------
__global__ __launch_bounds__(64) void gate_kernel(
    const float* __restrict__ y, const float* __restrict__ u,
    const float* __restrict__ Dp, const float* __restrict__ out_w,
    const float* __restrict__ out_b, float* __restrict__ gate) {
  const int c = blockIdx.x, b = blockIdx.y, d = threadIdx.x;
  const size_t i = ((size_t)b * 1536 + c) * 64 + d;
  float yt = y[((size_t)(b * 2) * 1536 + c) * 64 + d]
           + y[((size_t)(b * 2 + 1) * 1536 + c) * 64 + d]
           + Dp[d] * u[i];
  float v = yt * out_w[d];
  for (int o = 32; o > 0; o >>= 1) v += __shfl_down(v, o, 64);
  if (d == 0) gate[b * 1536 + c] = 1.0f / (1.0f + __expf(-(v + out_b[0])));
}

// ---------------------------------------------------------------------------
// Heads: out = h_relu @ pred_w + pred_b; aux = h_relu @ bird_w + bird_b.
// ---------------------------------------------------------------------------
__global__ __launch_bounds__(256) void head_kernel(
    const unsigned short* __restrict__ h,
    const float* __restrict__ pred_w, const float* __restrict__ pred_b,
    const float* __restrict__ bird_w, const float* __restrict__ bird_b,
    float* __restrict__ out) {
  const int idx = blockIdx.x * 256 + threadIdx.x;
  const int b = idx >> 14, p = idx & 16383;
  const unsigned short* hb = h + (size_t)b * 384 * HWO + p;
  float a0 = pred_b[0], a1 = pred_b[1], a2 = pred_b[2];
  float a3 = pred_b[3], a4 = pred_b[4], a5 = pred_b[5];
  float a6 = bird_b[0], a7 = bird_b[1];
  for (int o = 0; o < 384; o++) {
    const float hv = bf2f(hb[(size_t)o * HWO]);
    const float* pw = pred_w + o * 6;
    a0 = fmaf(hv, pw[0], a0);
    a1 = fmaf(hv, pw[1], a1);
    a2 = fmaf(hv, pw[2], a2);
    a3 = fmaf(hv, pw[3], a3);
    a4 = fmaf(hv, pw[4], a4);
    a5 = fmaf(hv, pw[5], a5);
    a6 = fmaf(hv, bird_w[o * 2 + 0], a6);
    a7 = fmaf(hv, bird_w[o * 2 + 1], a7);
  }
  float* ob = out + (size_t)b * 6 * HWO + p;
  ob[0] = a0; ob[HWO] = a1; ob[2 * HWO] = a2;
  ob[3 * HWO] = a3; ob[4 * HWO] = a4; ob[5 * HWO] = a5;
  float* ab = out + (size_t)12 * HWO + (size_t)b * 2 * HWO + p;
  ab[0] = a6; ab[HWO] = a7;
}

// ---------------------------------------------------------------------------
extern "C" void kernel_launch(void* const* d_in, const int* in_sizes, int n_in,
                              void* d_out, int out_size, void* d_ws, size_t ws_size,
                              hipStream_t stream) {
  const float* c1      = (const float*)d_in[0];
  const float* c2      = (const float*)d_in[1];
  const float* c3      = (const float*)d_in[2];
  const float* c4      = (const float*)d_in[3];
  const float* mlp1_w  = (const float*)d_in[4];
  const float* mlp1_b  = (const float*)d_in[5];
  const float* mlp2_w  = (const float*)d_in[6];
  const float* mlp2_b  = (const float*)d_in[7];
  const float* mlp3_w  = (const float*)d_in[8];
  const float* mlp3_b  = (const float*)d_in[9];
  const float* mlp4_w  = (const float*)d_in[10];
  const float* mlp4_b  = (const float*)d_in[11];
  const float* up2_w   = (const float*)d_in[12];
  const float* up2_b   = (const float*)d_in[13];
  const float* up4_w   = (const float*)d_in[14];
  const float* up4_b   = (const float*)d_in[15];
  const float* up8_w   = (const float*)d_in[16];
  const float* up8_b   = (const float*)d_in[17];
  const float* ssm_in_w    = (const float*)d_in[18];
  const float* ssm_in_b    = (const float*)d_in[19];
  const float* ssm_xproj_w = (const float*)d_in[20];
  const float* ssm_dt_w    = (const float*)d_in[21];
  const float* ssm_dt_b    = (const float*)d_in[22];
  const float* ssm_A_log   = (const float*)d_in[23];
  const float* ssm_D       = (const float*)d_in[24];
  const float* ssm_out_w   = (const float*)d_in[25];
  const float* ssm_out_b   = (const float*)d_in[26];
  const float* fuse_w  = (const float*)d_in[27];
  const float* bn_g    = (const float*)d_in[28];
  const float* bn_b    = (const float*)d_in[29];
  const float* bn_m    = (const float*)d_in[30];
  const float* bn_v    = (const float*)d_in[31];
  const float* pred_w  = (const float*)d_in[32];
  const float* pred_b  = (const float*)d_in[33];
  const float* bird_w  = (const float*)d_in[34];
  const float* bird_b  = (const float*)d_in[35];
  float* outp = (float*)d_out;
  (void)in_sizes; (void)n_in; (void)out_size; (void)ws_size;

  float* ws = (float*)d_ws;
  size_t off = 0;
  auto alloc = [&](size_t n) { float* p = ws + off; off += n; return p; };
  unsigned short* cc = (unsigned short*)alloc((size_t)CTOT * HWO);  // bf16 (B,1536,128,128)
  float* scratch = alloc(6291456);                    // p*/o*; later aliased by hbf
  float* bp4 = scratch;                 // 2*384*256
  float* bp3 = scratch + 196608;        // 2*384*1024
  float* bp2 = scratch + 983040;        // 2*384*4096
  float* bo4 = scratch + 4128768;       // 2*512*256
  float* bo3 = scratch + 4390912;       // 2*128*1024
  float* bo2 = scratch + 4653056;       // 2*32*4096
  unsigned short* hbf = (unsigned short*)scratch;     // 2*384*16384 bf16 (alias)
  float* sbuf = alloc(3072);
  float* ub   = alloc(196608);
  float2* dtdu = (float2*)alloc(393216);
  float* Bsb  = alloc(49152);
  float* Csb  = alloc(49152);
  float* yb   = alloc(393216);
  float* gteb = alloc(3072);
  float* scb  = alloc(384);
  float* shb  = alloc(384);
  unsigned short* wt0 = (unsigned short*)(ws + off);
  unsigned short* t1  = wt0;             // 96*384
  unsigned short* t2  = t1 + 36864;      // 96*384
  unsigned short* t3  = t2 + 36864;      // 192*384
  unsigned short* t4  = t3 + 73728;      // 384*384
  unsigned short* t8  = t4 + 147456;     // 384*512
  unsigned short* t4u = t8 + 196608;     // 384*128
  unsigned short* t2u = t4u + 49152;     // 384*32
  unsigned short* wg  = t2u + 12288;     // 2*384*1536

  // 0) batched weight transposes (bf16) + BN fold
  {
    TP7 sp;
    const float* Ws[7] = {mlp1_w, mlp2_w, mlp3_w, mlp4_w, up8_w, up4_w, up2_w};
    unsigned short* Ts[7] = {t1, t2, t3, t4, t8, t4u, t2u};
    const int Ks[7] = {96, 96, 192, 384, 384, 384, 384};
    const int Ns[7] = {384, 384, 384, 384, 512, 128, 32};
    int bs = 0;
    for (int i = 0; i < 7; i++) {
      sp.W[i] = Ws[i]; sp.T[i] = Ts[i]; sp.K[i] = Ks[i]; sp.N[i] = Ns[i];
      sp.bstart[i] = bs;
      bs += (Ks[i] * Ns[i] + 255) / 256;
    }
    sp.bstart[7] = bs;
    hipLaunchKernelGGL(transpose7_kernel, dim3(bs), dim3(256), 0, stream, sp);
  }
  hipLaunchKernelGGL(bnfold_kernel, dim3(2), dim3(256), 0, stream,
                     bn_g, bn_v, bn_m, bn_b, scb, shb);

  // 1) feature projections (MFMA)
  hipLaunchKernelGGL((mfma_gemm<96, 24, 6, true, true, false>), dim3(256, 2), dim3(256), 0, stream,
      (const void*)c1, t1, mlp1_b, nullptr, nullptr, (void*)(cc + (size_t)1152 * HWO),
      HWO, (long)96 * HWO, 0L, (long)CTOT * HWO);
  hipLaunchKernelGGL((mfma_gemm<384, 24, 6, true, false, false>), dim3(4, 2), dim3(256), 0, stream,
      (const void*)c4, t4, mlp4_b, nullptr, nullptr, (void*)bp4, 256, (long)384 * 256, 0L, (long)384 * 256);
  hipLaunchKernelGGL((mfma_gemm<192, 24, 6, true, false, false>), dim3(16, 2), dim3(256), 0, stream,
      (const void*)c3, t3, mlp3_b, nullptr, nullptr, (void*)bp3, 1024, (long)192 * 1024, 0L, (long)384 * 1024);
  hipLaunchKernelGGL((mfma_gemm<96, 24, 6, true, false, false>), dim3(64, 2), dim3(256), 0, stream,
      (const void*)c2, t2, mlp2_b, nullptr, nullptr, (void*)bp2, 4096, (long)96 * 4096, 0L, (long)384 * 4096);
  // 2) offset convs (MFMA)
  hipLaunchKernelGGL((mfma_gemm<384, 32, 8, true, false, false>), dim3(4, 2), dim3(256), 0, stream,
      (const void*)bp4, t8, up8_b, nullptr, nullptr, (void*)bo4, 256, (long)384 * 256, 0L, (long)512 * 256);
  hipLaunchKernelGGL((mfma_gemm<384, 8, 2, true, false, false>), dim3(16, 2), dim3(256), 0, stream,
      (const void*)bp3, t4u, up4_b, nullptr, nullptr, (void*)bo3, 1024, (long)384 * 1024, 0L, (long)128 * 1024);
  hipLaunchKernelGGL((mfma_gemm<384, 2, 1, false, false, false>), dim3(64, 2), dim3(256), 0, stream,
      (const void*)bp2, t2u, up2_b, nullptr, nullptr, (void*)bo2, 4096, (long)384 * 4096, 0L, (long)32 * 4096);
  // 3) dysample upsampling into cc (bf16)
  hipLaunchKernelGGL(upsample_kernel, dim3(HWO / 256, 4, 2), dim3(256), 0, stream,
                     bp4, bo4, cc, 3, 16, 16);
  hipLaunchKernelGGL(upsample_kernel, dim3(HWO / 256, 4, 2), dim3(256), 0, stream,
                     bp3, bo3, cc + (size_t)384 * HWO, 2, 32, 32);
  hipLaunchKernelGGL(upsample_kernel, dim3(HWO / 256, 4, 2), dim3(256), 0, stream,
                     bp2, bo2, cc + (size_t)768 * HWO, 1, 64, 64);
  // 4) spatial means
  hipLaunchKernelGGL(colmean_kernel, dim3(3072), dim3(256), 0, stream, cc, sbuf);
  // 5) ssm prep + parallel scan + gate
  hipLaunchKernelGGL(ssm_prep, dim3(3072), dim3(64), 0, stream,
                     sbuf, ssm_in_w, ssm_in_b, ssm_xproj_w, ssm_dt_w, ssm_dt_b,
                     ub, dtdu, Bsb, Csb);
  hipLaunchKernelGGL(ssm_scan_par, dim3(64, 2, 2), dim3(256), 0, stream,
                     dtdu, Bsb, Csb, ssm_A_log, yb);
  hipLaunchKernelGGL(gate_kernel, dim3(1536, 2), dim3(64), 0, stream,
                     yb, ub, ssm_D, ssm_out_w, ssm_out_b, gteb);
  // 6) gate-folded fuse weights (per batch), then fused GEMM + BN + ReLU
  hipLaunchKernelGGL(transpose_fuse, dim3((1536 * 384 + 255) / 256, 2), dim3(256), 0, stream,
                     fuse_w, gteb, wg);
  hipLaunchKernelGGL((mfma_gemm<1536, 24, 6, true, true, true>), dim3(256, 2), dim3(256), 0, stream,
      (const void*)cc, wg, nullptr, scb, shb, (void*)hbf,
      HWO, (long)CTOT * HWO, (long)384 * 1536, (long)384 * HWO);
  // 7) heads
  hipLaunchKernelGGL(head_kernel, dim3(128), dim3(256), 0, stream,
                     hbf, pred_w, pred_b, bird_w, bird_b, outp);
}

// Round 4
// 324.727 us; speedup vs baseline: 10.3272x; 1.5430x over previous
//
#include <hip/hip_runtime.h>
#include <cstddef>

#define HWO 16384   // 128*128
#define CTOT 1536

typedef __attribute__((ext_vector_type(8))) short bf16x8;
typedef __attribute__((ext_vector_type(4))) float f32x4;

__device__ inline unsigned short f2bf(float x) {
  union { float f; unsigned u; } v; v.f = x;
  unsigned r = v.u + 0x7FFFu + ((v.u >> 16) & 1u);
  return (unsigned short)(r >> 16);
}
__device__ inline float bf2f(unsigned short h) {
  union { unsigned u; float f; } v; v.u = ((unsigned)h) << 16; return v.f;
}

// ---------------------------------------------------------------------------
// Batched static weight transposes: W[K][N] f32 -> Wt[N][K] bf16 (7 specs).
// ---------------------------------------------------------------------------
struct TP7 {
  const float* W[7];
  unsigned short* T[7];
  int K[7], N[7], bstart[8];
};
__global__ __launch_bounds__(256) void transpose7_kernel(TP7 sp) {
  int s = 0;
#pragma unroll
  for (int i = 1; i < 7; i++) if ((int)blockIdx.x >= sp.bstart[i]) s = i;
  const int K = sp.K[s], N = sp.N[s];
  const int idx = (blockIdx.x - sp.bstart[s]) * 256 + threadIdx.x;
  if (idx >= K * N) return;
  const int k = idx / N, o = idx - k * N;
  sp.T[s][(size_t)o * K + k] = f2bf(sp.W[s][idx]);
}

// fuse_w transpose with per-batch gate fold: grid (blocks, 2)
__global__ __launch_bounds__(256) void transpose_fuse(
    const float* __restrict__ W, const float* __restrict__ gate,
    unsigned short* __restrict__ Wt) {
  const int b = blockIdx.y;
  const int idx = blockIdx.x * 256 + threadIdx.x;
  if (idx >= 1536 * 384) return;
  const int k = idx / 384, o = idx - k * 384;
  Wt[(size_t)b * 589824 + (size_t)o * 1536 + k] =
      f2bf(W[idx] * gate[b * 1536 + k]);
}

__global__ __launch_bounds__(256) void bnfold_kernel(
    const float* __restrict__ g, const float* __restrict__ var,
    const float* __restrict__ m, const float* __restrict__ bb,
    float* __restrict__ sc, float* __restrict__ sh) {
  const int o = blockIdx.x * 256 + threadIdx.x;
  if (o < 384) {
    const float s = g[o] * rsqrtf(var[o] + 1e-5f);
    sc[o] = s;
    sh[o] = bb[o] - m[o] * s;
  }
}

// ---------------------------------------------------------------------------
// Position-major MFMA GEMM: Y[b,p,o] = sum_k X[b,p,k] * W[k,o] (+bias/BN-relu)
// XMODE 1: X bf16 [B][P][K] (k contiguous -> pure vector staging)
// XMODE 0: X f32  [B][K][P] (channel-major input; transpose during staging)
// Wt: bf16 [(B)][N][K]. Tile: BM=WM*MT*16 pos x BN=WN*OT*16 o, BK=64 (32 if K%64).
// ---------------------------------------------------------------------------
template<int K, int WM, int WN, int MT, int OT, int XMODE, int OMODE>
__global__ __launch_bounds__(WM * WN * 64) void pm_gemm(
    const void* __restrict__ Xv, const unsigned short* __restrict__ Wt,
    const float* __restrict__ bias, const float* __restrict__ ep_a,
    const float* __restrict__ ep_b, void* __restrict__ Yv,
    int P, long x_bs, long wt_bs, long y_bs, int yrs, int ycol) {
  constexpr int BM = WM * MT * 16, BN = WN * OT * 16, NTH = WM * WN * 64;
  constexpr int BK = (K % 64 == 0) ? 64 : 32;
  constexpr int LST = BK + 8;   // row stride in shorts; +8 pad -> conflict-free
  static_assert(XMODE == 1 || BM == 128, "XMODE0 staging assumes BM=128");
  __shared__ unsigned short Alds[BM * LST];
  __shared__ unsigned short Blds[BN * LST];
  const int tid = threadIdx.x;
  const int w = tid >> 6, lane = tid & 63;
  const int wm = w / WN, wn = w % WN;
  const int b = blockIdx.z;
  const int p0 = blockIdx.x * BM;
  const int o0 = blockIdx.y * BN;
  const unsigned short* Wb = Wt + (long)b * wt_bs + (long)o0 * K;
  f32x4 acc[MT * OT];
#pragma unroll
  for (int i = 0; i < MT * OT; i++) acc[i] = (f32x4){0.f, 0.f, 0.f, 0.f};
  const int lr = lane & 15, lk = (lane >> 4) * 8;

  for (int kc = 0; kc < K; kc += BK) {
    if constexpr (XMODE == 1) {
      const unsigned short* Xb = (const unsigned short*)Xv + (long)b * x_bs;
#pragma unroll
      for (int it = 0; it < BM * (BK / 8) / NTH; it++) {
        const int idx = tid + it * NTH;
        const int r = idx / (BK / 8), ck = (idx % (BK / 8)) * 8;
        *(uint4*)&Alds[r * LST + ck] =
            *(const uint4*)(Xb + (long)(p0 + r) * K + kc + ck);
      }
    } else {
      const float* Xf = (const float*)Xv + (long)b * x_bs;
#pragma unroll
      for (int it = 0; it < BK * 32 / NTH; it++) {
        const int idx = tid + it * NTH;
        const int k = idx >> 5, pg = (idx & 31) * 4;
        const float4 v = *(const float4*)(Xf + (long)(kc + k) * P + p0 + pg);
        Alds[(pg + 0) * LST + k] = f2bf(v.x);
        Alds[(pg + 1) * LST + k] = f2bf(v.y);
        Alds[(pg + 2) * LST + k] = f2bf(v.z);
        Alds[(pg + 3) * LST + k] = f2bf(v.w);
      }
    }
#pragma unroll
    for (int it = 0; it < BN * (BK / 8) / NTH; it++) {
      const int idx = tid + it * NTH;
      const int r = idx / (BK / 8), ck = (idx % (BK / 8)) * 8;
      *(uint4*)&Blds[r * LST + ck] =
          *(const uint4*)(Wb + (long)r * K + kc + ck);
    }
    __syncthreads();
#pragma unroll
    for (int kk = 0; kk < BK; kk += 32) {
      bf16x8 af[MT];
#pragma unroll
      for (int mt = 0; mt < MT; mt++)
        af[mt] = *(const bf16x8*)&Alds[((wm * MT + mt) * 16 + lr) * LST + kk + lk];
#pragma unroll
      for (int ot = 0; ot < OT; ot++) {
        const bf16x8 bfr =
            *(const bf16x8*)&Blds[((wn * OT + ot) * 16 + lr) * LST + kk + lk];
#pragma unroll
        for (int mt = 0; mt < MT; mt++)
          acc[mt * OT + ot] = __builtin_amdgcn_mfma_f32_16x16x32_bf16(
              af[mt], bfr, acc[mt * OT + ot], 0, 0, 0);
      }
    }
    __syncthreads();
  }
  // C/D: col(lane&15)=o-row of B, row((lane>>4)*4+reg)=position
  const int r0 = (lane >> 4) * 4;
#pragma unroll
  for (int mt = 0; mt < MT; mt++) {
#pragma unroll
    for (int ot = 0; ot < OT; ot++) {
      const int o = o0 + (wn * OT + ot) * 16 + lr;
      const f32x4 r = acc[mt * OT + ot];
      const float bv = bias ? bias[o] : 0.f;
#pragma unroll
      for (int jj = 0; jj < 4; jj++) {
        const long row = p0 + (wm * MT + mt) * 16 + r0 + jj;
        float v = r[jj] + bv;
        if constexpr (OMODE == 2) v = fmaxf(fmaf(v, ep_a[o], ep_b[o]), 0.f);
        if constexpr (OMODE == 0)
          ((float*)Yv)[(long)b * y_bs + row * yrs + ycol + o] = v;
        else
          ((unsigned short*)Yv)[(long)b * y_bs + row * yrs + ycol + o] = f2bf(v);
      }
    }
  }
}

// ---------------------------------------------------------------------------
// DySample bilinear upsample, position-major: bp bf16 [HWs][384],
// bo f32 [HWs][offC], out -> cc bf16 [HWO][1536] at column ccol0+grp*96.
// ---------------------------------------------------------------------------
__global__ __launch_bounds__(256) void upsample_pm(
    const unsigned short* __restrict__ bp, const float* __restrict__ bo,
    unsigned short* __restrict__ cc, int ls, int H, int W, int offC, int ccol0) {
  const int b = blockIdx.z, grp = blockIdx.y;
  const int op = blockIdx.x * 256 + threadIdx.x;
  const int s = 1 << ls, ss = s * s;
  const int yo = op >> 7, xo = op & 127;
  const int h = yo >> ls, i = yo & (s - 1);
  const int w = xo >> ls, j = xo & (s - 1);
  const int HWs = H * W;
  const int sp = h * W + w;
  const float* offp = bo + ((size_t)b * HWs + sp) * offC;
  const float cx = offp[grp * ss + i * s + j];
  const float cy = offp[(4 + grp) * ss + i * s + j];
  const float inv_s = 1.0f / (float)s;
  const float offx = cx * 0.25f + ((float)j - (s - 1) * 0.5f) * inv_s;
  const float offy = cy * 0.25f + ((float)i - (s - 1) * 0.5f) * inv_s;
  float xf = fminf(fmaxf((float)w + offx, 0.0f), (float)(W - 1));
  float yf = fminf(fmaxf((float)h + offy, 0.0f), (float)(H - 1));
  float x0f = floorf(xf), y0f = floorf(yf);
  int x0 = (int)x0f, y0 = (int)y0f;
  int x1 = min(x0 + 1, W - 1), y1 = min(y0 + 1, H - 1);
  float wx = xf - x0f, wy = yf - y0f;
  float w00 = (1.f - wx) * (1.f - wy), w01 = wx * (1.f - wy);
  float w10 = (1.f - wx) * wy,         w11 = wx * wy;
  const unsigned short* pb = bp + (size_t)b * HWs * 384 + grp * 96;
  const unsigned short* q00 = pb + (size_t)(y0 * W + x0) * 384;
  const unsigned short* q01 = pb + (size_t)(y0 * W + x1) * 384;
  const unsigned short* q10 = pb + (size_t)(y1 * W + x0) * 384;
  const unsigned short* q11 = pb + (size_t)(y1 * W + x1) * 384;
  unsigned short* occ = cc + ((size_t)b * HWO + op) * CTOT + ccol0 + grp * 96;
#pragma unroll
  for (int c8 = 0; c8 < 96; c8 += 8) {
    const uint4 v00 = *(const uint4*)(q00 + c8);
    const uint4 v01 = *(const uint4*)(q01 + c8);
    const uint4 v10 = *(const uint4*)(q10 + c8);
    const uint4 v11 = *(const uint4*)(q11 + c8);
    const unsigned short* s00 = (const unsigned short*)&v00;
    const unsigned short* s01 = (const unsigned short*)&v01;
    const unsigned short* s10 = (const unsigned short*)&v10;
    const unsigned short* s11 = (const unsigned short*)&v11;
    unsigned short r8[8];
#pragma unroll
    for (int jj = 0; jj < 8; jj++) {
      const float v = w00 * bf2f(s00[jj]) + w01 * bf2f(s01[jj]) +
                      w10 * bf2f(s10[jj]) + w11 * bf2f(s11[jj]);
      r8[jj] = f2bf(v);
    }
    *(uint4*)(occ + c8) = *(const uint4*)r8;
  }
}

// ---------------------------------------------------------------------------
// Partial column sums of cc [p][c]: grid (3 c-chunks of 512, 32 p-chunks, B).
// part[pchunk][b*1536 + c] written; ssm_prep reduces the 32 partials.
// ---------------------------------------------------------------------------
__global__ __launch_bounds__(256) void colmean_pm(
    const unsigned short* __restrict__ cc, float* __restrict__ part) {
  const int c0 = blockIdx.x * 512;
  const int p0 = blockIdx.y * 512;
  const int b = blockIdx.z;
  const int t = threadIdx.x;
  const int c8 = (t & 63) * 8;
  const int rg = t >> 6;
  float a[8];
#pragma unroll
  for (int jj = 0; jj < 8; jj++) a[jj] = 0.f;
  const unsigned short* base =
      cc + ((size_t)b * HWO + p0 + rg) * CTOT + c0 + c8;
  for (int it = 0; it < 128; it++) {
    const uint4 v = *(const uint4*)(base + (size_t)it * 4 * CTOT);
    const unsigned short* sv = (const unsigned short*)&v;
#pragma unroll
    for (int jj = 0; jj < 8; jj++) a[jj] += bf2f(sv[jj]);
  }
  __shared__ float red[4][512];
#pragma unroll
  for (int jj = 0; jj < 8; jj++) red[rg][c8 + jj] = a[jj];
  __syncthreads();
  for (int col = t; col < 512; col += 256) {
    const float sum = red[0][col] + red[1][col] + red[2][col] + red[3][col];
    part[(size_t)blockIdx.y * 3072 + b * 1536 + c0 + col] = sum;
  }
}

// ---------------------------------------------------------------------------
// SSM prep: sum the 32 partials -> mean; per (b,c): u(64), proj(33), dt.
// ---------------------------------------------------------------------------
__global__ __launch_bounds__(64) void ssm_prep(
    const float* __restrict__ part, const float* __restrict__ in_w,
    const float* __restrict__ in_b, const float* __restrict__ xproj_w,
    const float* __restrict__ dt_w, const float* __restrict__ dt_b,
    float* __restrict__ u_out, float2* __restrict__ dtdu_out,
    float* __restrict__ Bs_out, float* __restrict__ Cs_out) {
  const int bc = blockIdx.x;
  const int d = threadIdx.x;
  float a = (d < 32) ? part[(size_t)d * 3072 + bc] : 0.f;
  a += __shfl_xor(a, 1, 64);
  a += __shfl_xor(a, 2, 64);
  a += __shfl_xor(a, 4, 64);
  a += __shfl_xor(a, 8, 64);
  a += __shfl_xor(a, 16, 64);
  a += __shfl_xor(a, 32, 64);
  const float sv = a * (1.0f / HWO);
  const float u = sv * in_w[d] + in_b[d];
  __shared__ float ush[64];
  __shared__ float proj[33];
  ush[d] = u;
  __syncthreads();
  if (d < 33) {
    float acc = 0.f;
    for (int k = 0; k < 64; k++) acc = fmaf(ush[k], xproj_w[k * 33 + d], acc);
    proj[d] = acc;
  }
  __syncthreads();
  float dtv = proj[0] * dt_w[d] + dt_b[d];
  dtv = (dtv > 20.0f) ? dtv : log1pf(__expf(dtv));   // softplus
  u_out[(size_t)bc * 64 + d] = u;
  dtdu_out[(size_t)bc * 64 + d] = make_float2(dtv, dtv * u);
  if (d < 16) {
    Bs_out[(size_t)bc * 16 + d] = proj[1 + d];
    Cs_out[(size_t)bc * 16 + d] = proj[17 + d];
  }
}

// ---------------------------------------------------------------------------
// Parallel associative scan. grid = (64 d, 2 dir, 2 b), block = 256.
// ---------------------------------------------------------------------------
__global__ __launch_bounds__(256) void ssm_scan_par(
    const float2* __restrict__ dtdu, const float* __restrict__ Bs,
    const float* __restrict__ Cs, const float* __restrict__ A_log,
    float* __restrict__ y) {
  const int d = blockIdx.x, dir = blockIdx.y, b = blockIdx.z;
  const int t = threadIdx.x;
  const int j = t >> 4, n = t & 15;
  const float A = -__expf(A_log[d * 16 + n]);
  const int s0 = j * 96;
  const int c0 = dir ? (1535 - s0) : s0;
  const int step = dir ? -1 : 1;
  const float2* dbase = dtdu + (size_t)b * 1536 * 64 + (size_t)c0 * 64 + d;
  const float* bbase = Bs + (size_t)b * 1536 * 16 + (size_t)c0 * 16 + n;
  const float* cbase = Cs + (size_t)b * 1536 * 16 + (size_t)c0 * 16 + n;
  const long dstep = (long)step * 64;
  const long bstep = (long)step * 16;

  float Ap = 1.f, Bp = 0.f;
  {
    const float2* dp = dbase;
    const float* bp = bbase;
    float2 td = *dp;
    float Bv = *bp;
    for (int i = 0; i < 96; i++) {
      const float2 tdc = td;
      const float Bc = Bv;
      dp += dstep; bp += bstep;
      if (i + 1 < 96) { td = *dp; Bv = *bp; }
      const float a = __expf(tdc.x * A);
      Bp = fmaf(a, Bp, tdc.y * Bc);
      Ap *= a;
    }
  }
  __shared__ float sA[16][16], sB[16][16];
  sA[j][n] = Ap;
  sB[j][n] = Bp;
  __syncthreads();
  float H = 0.f;
  for (int jj = 0; jj < j; jj++) H = fmaf(sA[jj][n], H, sB[jj][n]);

  float* yb = y + (size_t)(b * 2 + dir) * 1536 * 64;
  {
    const float2* dp = dbase;
    const float* bp = bbase;
    const float* cp = cbase;
    float2 td = *dp;
    float Bv = *bp;
    float Cv = *cp;
    float h = H;
    int c = c0;
    for (int i = 0; i < 96; i++) {
      const float2 tdc = td;
      const float Bc = Bv, Cc = Cv;
      dp += dstep; bp += bstep; cp += bstep;
      if (i + 1 < 96) { td = *dp; Bv = *bp; Cv = *cp; }
      const float a = __expf(tdc.x * A);
      h = fmaf(a, h, tdc.y * Bc);
      float pr = h * Cc;
      pr += __shfl_xor(pr, 1, 64);
      pr += __shfl_xor(pr, 2, 64);
      pr += __shfl_xor(pr, 4, 64);
      pr += __shfl_xor(pr, 8, 64);
      if (n == 0) yb[(size_t)c * 64 + d] = pr;
      c += step;
    }
  }
}

// ---------------------------------------------------------------------------
// Gate: yt = y_fwd + y_bwd + D*u; gate = sigmoid(yt . out_w + out_b).
// ---------------------------------------------------------------------------
__global__ __launch_bounds__(64) void gate_kernel(
    const float* __restrict__ y, const float* __restrict__ u,
    const float* __restrict__ Dp, const float* __restrict__ out_w,
    const float* __restrict__ out_b, float* __restrict__ gate) {
  const int c = blockIdx.x, b = blockIdx.y, d = threadIdx.x;
  const size_t i = ((size_t)b * 1536 + c) * 64 + d;
  float yt = y[((size_t)(b * 2) * 1536 + c) * 64 + d]
           + y[((size_t)(b * 2 + 1) * 1536 + c) * 64 + d]
           + Dp[d] * u[i];
  float v = yt * out_w[d];
  for (int o = 32; o > 0; o >>= 1) v += __shfl_down(v, o, 64);
  if (d == 0) gate[b * 1536 + c] = 1.0f / (1.0f + __expf(-(v + out_b[0])));
}

// ---------------------------------------------------------------------------
// Heads (position-major h): per-p dot over contiguous 384 bf16.
// ---------------------------------------------------------------------------
__global__ __launch_bounds__(256) void head_pm(
    const unsigned short* __restrict__ h,
    const float* __restrict__ pred_w, const float* __restrict__ pred_b,
    const float* __restrict__ bird_w, const float* __restrict__ bird_b,
    float* __restrict__ out) {
  const int idx = blockIdx.x * 256 + threadIdx.x;
  const int b = idx >> 14, p = idx & 16383;
  const unsigned short* hb = h + ((size_t)b * HWO + p) * 384;
  float a0 = pred_b[0], a1 = pred_b[1], a2 = pred_b[2];
  float a3 = pred_b[3], a4 = pred_b[4], a5 = pred_b[5];
  float a6 = bird_b[0], a7 = bird_b[1];
  for (int c8 = 0; c8 < 384; c8 += 8) {
    const uint4 v = *(const uint4*)(hb + c8);
    const unsigned short* sv = (const unsigned short*)&v;
#pragma unroll
    for (int jj = 0; jj < 8; jj++) {
      const int o = c8 + jj;
      const float hv = bf2f(sv[jj]);
      const float* pw = pred_w + o * 6;
      a0 = fmaf(hv, pw[0], a0);
      a1 = fmaf(hv, pw[1], a1);
      a2 = fmaf(hv, pw[2], a2);
      a3 = fmaf(hv, pw[3], a3);
      a4 = fmaf(hv, pw[4], a4);
      a5 = fmaf(hv, pw[5], a5);
      a6 = fmaf(hv, bird_w[o * 2 + 0], a6);
      a7 = fmaf(hv, bird_w[o * 2 + 1], a7);
    }
  }
  float* ob = out + (size_t)b * 6 * HWO + p;
  ob[0] = a0; ob[HWO] = a1; ob[2 * HWO] = a2;
  ob[3 * HWO] = a3; ob[4 * HWO] = a4; ob[5 * HWO] = a5;
  float* ab = out + (size_t)12 * HWO + (size_t)b * 2 * HWO + p;
  ab[0] = a6; ab[HWO] = a7;
}

// ---------------------------------------------------------------------------
extern "C" void kernel_launch(void* const* d_in, const int* in_sizes, int n_in,
                              void* d_out, int out_size, void* d_ws, size_t ws_size,
                              hipStream_t stream) {
  const float* c1      = (const float*)d_in[0];
  const float* c2      = (const float*)d_in[1];
  const float* c3      = (const float*)d_in[2];
  const float* c4      = (const float*)d_in[3];
  const float* mlp1_w  = (const float*)d_in[4];
  const float* mlp1_b  = (const float*)d_in[5];
  const float* mlp2_w  = (const float*)d_in[6];
  const float* mlp2_b  = (const float*)d_in[7];
  const float* mlp3_w  = (const float*)d_in[8];
  const float* mlp3_b  = (const float*)d_in[9];
  const float* mlp4_w  = (const float*)d_in[10];
  const float* mlp4_b  = (const float*)d_in[11];
  const float* up2_w   = (const float*)d_in[12];
  const float* up2_b   = (const float*)d_in[13];
  const float* up4_w   = (const float*)d_in[14];
  const float* up4_b   = (const float*)d_in[15];
  const float* up8_w   = (const float*)d_in[16];
  const float* up8_b   = (const float*)d_in[17];
  const float* ssm_in_w    = (const float*)d_in[18];
  const float* ssm_in_b    = (const float*)d_in[19];
  const float* ssm_xproj_w = (const float*)d_in[20];
  const float* ssm_dt_w    = (const float*)d_in[21];
  const float* ssm_dt_b    = (const float*)d_in[22];
  const float* ssm_A_log   = (const float*)d_in[23];
  const float* ssm_D       = (const float*)d_in[24];
  const float* ssm_out_w   = (const float*)d_in[25];
  const float* ssm_out_b   = (const float*)d_in[26];
  const float* fuse_w  = (const float*)d_in[27];
  const float* bn_g    = (const float*)d_in[28];
  const float* bn_b    = (const float*)d_in[29];
  const float* bn_m    = (const float*)d_in[30];
  const float* bn_v    = (const float*)d_in[31];
  const float* pred_w  = (const float*)d_in[32];
  const float* pred_b  = (const float*)d_in[33];
  const float* bird_w  = (const float*)d_in[34];
  const float* bird_b  = (const float*)d_in[35];
  float* outp = (float*)d_out;
  (void)in_sizes; (void)n_in; (void)out_size; (void)ws_size;

  float* ws = (float*)d_ws;
  size_t off = 0;
  auto alloc = [&](size_t n) { float* p = ws + off; off += n; return p; };
  // cc: bf16 [B][16384][1536]
  unsigned short* cc = (unsigned short*)alloc(25165824);
  float* scratch = alloc(6291456);
  unsigned short* bp4 = (unsigned short*)scratch;      // bf16 [2][256][384]
  unsigned short* bp3 = bp4 + 196608;                  // bf16 [2][1024][384]
  unsigned short* bp2 = bp3 + 786432;                  // bf16 [2][4096][384]
  float* bo4 = scratch + 2064384;                      // f32 [2][256][512]
  float* bo3 = bo4 + 262144;                           // f32 [2][1024][128]
  float* bo2 = bo3 + 262144;                           // f32 [2][4096][32]
  unsigned short* hbf = (unsigned short*)scratch;      // bf16 [2][16384][384] alias
  float* part = alloc(98304);                          // [32][2][1536]
  float* ub   = alloc(196608);
  float2* dtdu = (float2*)alloc(393216);
  float* Bsb  = alloc(49152);
  float* Csb  = alloc(49152);
  float* yb   = alloc(393216);
  float* gteb = alloc(3072);
  float* scb  = alloc(384);
  float* shb  = alloc(384);
  unsigned short* t1  = (unsigned short*)(ws + off);   // 96*384
  unsigned short* t2  = t1 + 36864;      // 96*384
  unsigned short* t3  = t2 + 36864;      // 192*384
  unsigned short* t4  = t3 + 73728;      // 384*384
  unsigned short* t8  = t4 + 147456;     // 384*512
  unsigned short* t4u = t8 + 196608;     // 384*128
  unsigned short* t2u = t4u + 49152;     // 384*32
  unsigned short* wg  = t2u + 12288;     // 2*384*1536

  // 0) batched weight transposes (bf16) + BN fold
  {
    TP7 sp;
    const float* Ws[7] = {mlp1_w, mlp2_w, mlp3_w, mlp4_w, up8_w, up4_w, up2_w};
    unsigned short* Ts[7] = {t1, t2, t3, t4, t8, t4u, t2u};
    const int Ks[7] = {96, 96, 192, 384, 384, 384, 384};
    const int Ns[7] = {384, 384, 384, 384, 512, 128, 32};
    int bs = 0;
    for (int i = 0; i < 7; i++) {
      sp.W[i] = Ws[i]; sp.T[i] = Ts[i]; sp.K[i] = Ks[i]; sp.N[i] = Ns[i];
      sp.bstart[i] = bs;
      bs += (Ks[i] * Ns[i] + 255) / 256;
    }
    sp.bstart[7] = bs;
    hipLaunchKernelGGL(transpose7_kernel, dim3(bs), dim3(256), 0, stream, sp);
  }
  hipLaunchKernelGGL(bnfold_kernel, dim3(2), dim3(256), 0, stream,
                     bn_g, bn_v, bn_m, bn_b, scb, shb);

  // 1) feature projections (position-major outputs)
  hipLaunchKernelGGL((pm_gemm<384, 2, 2, 4, 6, 0, 1>), dim3(2, 2, 2), dim3(256), 0, stream,
      (const void*)c4, t4, mlp4_b, nullptr, nullptr, (void*)bp4,
      256, (long)384 * 256, 0L, (long)256 * 384, 384, 0);
  hipLaunchKernelGGL((pm_gemm<192, 2, 2, 4, 6, 0, 1>), dim3(8, 2, 2), dim3(256), 0, stream,
      (const void*)c3, t3, mlp3_b, nullptr, nullptr, (void*)bp3,
      1024, (long)192 * 1024, 0L, (long)1024 * 384, 384, 0);
  hipLaunchKernelGGL((pm_gemm<96, 2, 2, 4, 6, 0, 1>), dim3(32, 2, 2), dim3(256), 0, stream,
      (const void*)c2, t2, mlp2_b, nullptr, nullptr, (void*)bp2,
      4096, (long)96 * 4096, 0L, (long)4096 * 384, 384, 0);
  hipLaunchKernelGGL((pm_gemm<96, 2, 2, 4, 6, 0, 1>), dim3(128, 2, 2), dim3(256), 0, stream,
      (const void*)c1, t1, mlp1_b, nullptr, nullptr, (void*)cc,
      16384, (long)96 * 16384, 0L, (long)16384 * 1536, 1536, 1152);
  // 2) offset convs
  hipLaunchKernelGGL((pm_gemm<384, 2, 2, 4, 4, 1, 0>), dim3(2, 4, 2), dim3(256), 0, stream,
      (const void*)bp4, t8, up8_b, nullptr, nullptr, (void*)bo4,
      256, (long)256 * 384, 0L, (long)256 * 512, 512, 0);
  hipLaunchKernelGGL((pm_gemm<384, 2, 2, 4, 4, 1, 0>), dim3(8, 1, 2), dim3(256), 0, stream,
      (const void*)bp3, t4u, up4_b, nullptr, nullptr, (void*)bo3,
      1024, (long)1024 * 384, 0L, (long)1024 * 128, 128, 0);
  hipLaunchKernelGGL((pm_gemm<384, 4, 1, 2, 2, 1, 0>), dim3(32, 1, 2), dim3(256), 0, stream,
      (const void*)bp2, t2u, up2_b, nullptr, nullptr, (void*)bo2,
      4096, (long)4096 * 384, 0L, (long)4096 * 32, 32, 0);
  // 3) dysample upsampling into cc (vectorized channel-contiguous)
  hipLaunchKernelGGL(upsample_pm, dim3(64, 4, 2), dim3(256), 0, stream,
                     bp4, bo4, cc, 3, 16, 16, 512, 0);
  hipLaunchKernelGGL(upsample_pm, dim3(64, 4, 2), dim3(256), 0, stream,
                     bp3, bo3, cc, 2, 32, 32, 128, 384);
  hipLaunchKernelGGL(upsample_pm, dim3(64, 4, 2), dim3(256), 0, stream,
                     bp2, bo2, cc, 1, 64, 64, 32, 768);
  // 4) spatial mean partials
  hipLaunchKernelGGL(colmean_pm, dim3(3, 32, 2), dim3(256), 0, stream, cc, part);
  // 5) ssm prep + parallel scan + gate
  hipLaunchKernelGGL(ssm_prep, dim3(3072), dim3(64), 0, stream,
                     part, ssm_in_w, ssm_in_b, ssm_xproj_w, ssm_dt_w, ssm_dt_b,
                     ub, dtdu, Bsb, Csb);
  hipLaunchKernelGGL(ssm_scan_par, dim3(64, 2, 2), dim3(256), 0, stream,
                     dtdu, Bsb, Csb, ssm_A_log, yb);
  hipLaunchKernelGGL(gate_kernel, dim3(1536, 2), dim3(64), 0, stream,
                     yb, ub, ssm_D, ssm_out_w, ssm_out_b, gteb);
  // 6) gate-folded fuse weights, then fused GEMM + BN + ReLU
  hipLaunchKernelGGL(transpose_fuse, dim3((1536 * 384 + 255) / 256, 2), dim3(256), 0, stream,
                     fuse_w, gteb, wg);
  hipLaunchKernelGGL((pm_gemm<1536, 2, 2, 4, 6, 1, 2>), dim3(128, 2, 2), dim3(256), 0, stream,
      (const void*)cc, wg, nullptr, scb, shb, (void*)hbf,
      16384, (long)16384 * 1536, (long)589824, (long)16384 * 384, 384, 0);
  // 7) heads
  hipLaunchKernelGGL(head_pm, dim3(128), dim3(256), 0, stream,
                     hbf, pred_w, pred_b, bird_w, bird_b, outp);
}